// Round 13
// baseline (7876.598 us; speedup 1.0000x reference)
//
#include <hip/hip_runtime.h>
#include <hip/hip_fp16.h>
#include <math.h>

#define HIDDEN 300
#define ATOM_FDIM 136
#define BOND_IN 148
#define MAX_NB 6
#define N_MOLS 4096
#define APM 32
#define N_ATOMS (N_MOLS*APM)
#define N_BONDS (2*N_ATOMS)

#define BK 16
#define BM 64
#define ASTR 68     // fp32-GEMM A-tile row stride (words)
#define BSTR 304    // fp32-GEMM B-tile row stride (words)

// Wt (split-bf16, transposed) geometry: [304 cols][320 k] per split
#define WT_C 304
#define WT_K 320

typedef unsigned short u16;
typedef short bf16x8 __attribute__((ext_vector_type(8)));
typedef float f32x4  __attribute__((ext_vector_type(4)));

// Fallback scratch if ws_size too small (same float count as the layout below):
// 2*WB (binput_h, msgA, msgB, acc_h as halves) + 3*WA + hsum + wt
__device__ float g_scratch[2ull * N_BONDS * HIDDEN + 3ull * N_ATOMS * HIDDEN
                           + (size_t)N_MOLS * HIDDEN + WT_C * WT_K];

__device__ __forceinline__ u16 bf16_rne(float x) {
    unsigned u = __float_as_uint(x);
    unsigned r = (u + 0x7fffu + ((u >> 16) & 1u)) >> 16;
    return (u16)r;
}
__device__ __forceinline__ float bf16_f(u16 h) {
    return __uint_as_float(((unsigned)h) << 16);
}
__device__ __forceinline__ void st_h4(__half* p, float a, float b, float c, float d) {
    *(__half2*)(p)     = __floats2half2_rn(a, b);
    *(__half2*)(p + 2) = __floats2half2_rn(c, d);
}

// ---------------------------------------------------------------------------
// Prep: Wt_hi/Wt_lo[col][k] = split-bf16 of W_h[k][col], zero-padded to 304x320
// ---------------------------------------------------------------------------
__global__ __launch_bounds__(256)
void wt_prep(const float* __restrict__ W, u16* __restrict__ wt_hi, u16* __restrict__ wt_lo)
{
    const int i = blockIdx.x * 256 + threadIdx.x;
    if (i >= WT_C * WT_K) return;
    const int c = i / WT_K, k = i - c * WT_K;
    float w = (c < HIDDEN && k < HIDDEN) ? W[(size_t)k * HIDDEN + c] : 0.f;
    const u16 hi = bf16_rne(w);
    const u16 lo = bf16_rne(w - bf16_f(hi));
    wt_hi[i] = hi;
    wt_lo[i] = lo;
}

// ---------------------------------------------------------------------------
// Message-passing step, K-column-blocked two-pass (L3-hot gather):
//  PASS 0 (kbeg=0,   5 K-steps): acc_h = fp16( gather6(msg[:,0:160]) @ W[0:160,:] )
//  PASS 1 (kbeg=160, 5 K-steps): out0 = fp16(relu(binput + acc_h + gather@W[160:,:]))
// Per pass the gather touches only a ~100 MB column slice of msg -> L3-resident
// (acc/binput streams use nontemporal hints so they don't evict it).
// Body = R8-proven stage/MFMA alternation (BM=64, 2 barriers/K-step).
// Split-bf16 3-product math (fp32-equivalent); D map (m89): col=lane&15,
// row=(lane>>4)*4+j. Stage reads may run past a row's 300 halves into the
// next row (finite fp16) x zero-padded Wt -> products vanish (proven R7/R8).
// ---------------------------------------------------------------------------
template<int PASS>
__global__ __launch_bounds__(512, 4)
void mp_mfma(const __half* __restrict__ msg,
             const int*   __restrict__ graph,
             const u16*   __restrict__ wt_hi,
             const u16*   __restrict__ wt_lo,
             const __half* __restrict__ binput,
             __half* __restrict__ accb,
             __half* __restrict__ out0,
             int kbeg)
{
    __shared__ u16 Ahi[64 * 40];   // row stride 40 u16 = 80B (16B-aligned)
    __shared__ u16 Alo[64 * 40];
    __shared__ int gx[64 * MAX_NB];

    const int tid  = threadIdx.x;
    const int row0 = blockIdx.x * 64;

    if (tid < 64 * MAX_NB) gx[tid] = graph[(size_t)row0 * MAX_NB + tid];
    __syncthreads();

    const int w  = tid >> 6;          // wave 0..7
    const int l  = tid & 63;
    const int g  = l >> 4;            // k-chunk 0..3
    const int mr = (w & 3) * 16 + (l & 15);      // A-frag row (block-local)
    const int tbase = (w >> 2) ? 10 : 0;         // n-tile group
    const int ntile = (w >> 2) ? 9 : 10;

    const int sr = tid >> 3;          // stage row 0..63
    const int sk = (tid & 7) * 4;     // stage k-offset 0..28
    const __half* rp0; const __half* rp1; const __half* rp2;
    const __half* rp3; const __half* rp4; const __half* rp5;
    {
        const int* sg = &gx[sr * MAX_NB];
        rp0 = msg + (size_t)sg[0] * HIDDEN + sk;
        rp1 = msg + (size_t)sg[1] * HIDDEN + sk;
        rp2 = msg + (size_t)sg[2] * HIDDEN + sk;
        rp3 = msg + (size_t)sg[3] * HIDDEN + sk;
        rp4 = msg + (size_t)sg[4] * HIDDEN + sk;
        rp5 = msg + (size_t)sg[5] * HIDDEN + sk;
    }

    f32x4 acc[10];
#pragma unroll
    for (int t = 0; t < 10; ++t) acc[t] = (f32x4){0.f, 0.f, 0.f, 0.f};

#pragma unroll
    for (int s = 0; s < 5; ++s) {
        const int k0 = kbeg + 32 * s;
        // ---- stage: gather-sum fp32 -> split bf16 hi/lo -> LDS (R8 style)
        float s0 = 0.f, s1 = 0.f, s2 = 0.f, s3 = 0.f;
        {
            const uint2 q0 = *(const uint2*)(rp0 + k0);
            const uint2 q1 = *(const uint2*)(rp1 + k0);
            const uint2 q2 = *(const uint2*)(rp2 + k0);
            const uint2 q3 = *(const uint2*)(rp3 + k0);
            const uint2 q4 = *(const uint2*)(rp4 + k0);
            const uint2 q5 = *(const uint2*)(rp5 + k0);
            const uint2 qs[6] = {q0, q1, q2, q3, q4, q5};
#pragma unroll
            for (int j = 0; j < 6; ++j) {
                const float2 a0 = __half22float2(*(const __half2*)&qs[j].x);
                const float2 a1 = __half22float2(*(const __half2*)&qs[j].y);
                s0 += a0.x; s1 += a0.y; s2 += a1.x; s3 += a1.y;
            }
        }
        const u16 h0 = bf16_rne(s0), h1 = bf16_rne(s1), h2 = bf16_rne(s2), h3 = bf16_rne(s3);
        const u16 e0 = bf16_rne(s0 - bf16_f(h0)), e1 = bf16_rne(s1 - bf16_f(h1));
        const u16 e2 = bf16_rne(s2 - bf16_f(h2)), e3 = bf16_rne(s3 - bf16_f(h3));
        uint2 ph, pl;
        ph.x = (unsigned)h0 | ((unsigned)h1 << 16);
        ph.y = (unsigned)h2 | ((unsigned)h3 << 16);
        pl.x = (unsigned)e0 | ((unsigned)e1 << 16);
        pl.y = (unsigned)e2 | ((unsigned)e3 << 16);
        *(uint2*)&Ahi[sr * 40 + sk] = ph;
        *(uint2*)&Alo[sr * 40 + sk] = pl;
        __syncthreads();

        // ---- MFMA phase: A frags from LDS, B frags from L2-resident Wt
        const bf16x8 ahi = *(const bf16x8*)&Ahi[mr * 40 + 8 * g];
        const bf16x8 alo = *(const bf16x8*)&Alo[mr * 40 + 8 * g];
        const int kb = k0 + 8 * g;
#pragma unroll
        for (int t = 0; t < 10; ++t) {
            if (t < ntile) {
                const int cn = 16 * (tbase + t) + (l & 15);
                const bf16x8 bhi = *(const bf16x8*)&wt_hi[(size_t)cn * WT_K + kb];
                const bf16x8 blo = *(const bf16x8*)&wt_lo[(size_t)cn * WT_K + kb];
                acc[t] = __builtin_amdgcn_mfma_f32_16x16x32_bf16(ahi, bhi, acc[t], 0, 0, 0);
                acc[t] = __builtin_amdgcn_mfma_f32_16x16x32_bf16(ahi, blo, acc[t], 0, 0, 0);
                acc[t] = __builtin_amdgcn_mfma_f32_16x16x32_bf16(alo, bhi, acc[t], 0, 0, 0);
            }
        }
        __syncthreads();
    }

    // ---- epilogue: D[row=(l>>4)*4+j][col=l&15] per tile
    const u16* bin_u = (const u16*)binput;
    const u16* acc_u = (const u16*)accb;
#pragma unroll
    for (int t = 0; t < 10; ++t) {
        if (t < ntile) {
            const int col = 16 * (tbase + t) + (l & 15);
            if (col < HIDDEN) {
#pragma unroll
                for (int j = 0; j < 4; ++j) {
                    const size_t off = (size_t)(row0 + (w & 3) * 16 + 4 * g + j) * HIDDEN + col;
                    if (PASS == 0) {
                        // partial sum -> fp16, nontemporal (don't evict msg from L3)
                        const __half hv = __float2half(acc[t][j]);
                        __builtin_nontemporal_store(__half_as_ushort(hv), (u16*)&accb[off]);
                    } else {
                        const float bi = __half2float(__ushort_as_half(
                            __builtin_nontemporal_load(bin_u + off)));
                        const float ac = __half2float(__ushort_as_half(
                            __builtin_nontemporal_load(acc_u + off)));
                        out0[off] = __float2half(fmaxf(bi + ac + acc[t][j], 0.f));
                    }
                }
            }
        }
    }
}

// ---------------------------------------------------------------------------
// fp32 fused GEMM family (R6/R7/R8-proven skeleton). 512 threads, BM=64, BK=16.
//  MODE 0: A=fbonds[lda]            -> out0=fp16(A@W), out1=fp16(relu(A@W))
//  MODE 2: A=concat(fatoms, gather from fp16 msg) -> out0=relu(A@W + bias)
//  MODE 3: A dense [lda]            -> out0=A@W
//  MODE 4: A dense (P_all)          -> out0[mol]=(hsum+sum_rows relu(A@W+bias))/32
// ---------------------------------------------------------------------------
template<int MODE>
__global__ __launch_bounds__(512)
void gemm_fused(const float* __restrict__ Adense, int lda,
                const void*  __restrict__ msgv,
                const int*   __restrict__ graph,
                const float* __restrict__ W,
                const float* __restrict__ bias,
                const float* __restrict__ hsum,
                float* __restrict__ out0,
                float* __restrict__ out1,
                int K)
{
    __shared__ float As[BK * ASTR];
    __shared__ float Bs[BK * BSTR];
    __shared__ int   gx[BM * MAX_NB];

    const int tid  = threadIdx.x;
    const int wave = tid >> 6;
    const int lane = tid & 63;
    const int row0 = blockIdx.x * BM;
    const int c0   = 4 * lane;
    const bool has4 = (lane < HIDDEN - 256);
    const int  c4   = has4 ? (256 + lane) : 256;

    if (MODE == 2) {
        if (tid < BM * MAX_NB) gx[tid] = graph[(size_t)row0 * MAX_NB + tid];
        __syncthreads();
    }

    float acc[8][5];
#pragma unroll
    for (int r = 0; r < 8; ++r)
#pragma unroll
        for (int c = 0; c < 5; ++c) acc[r][c] = 0.f;

    const int nk = (K + BK - 1) / BK;
    for (int kt = 0; kt < nk; ++kt) {
        const int k0 = kt * BK;
        for (int i = tid; i < BK * 300; i += 512) {
            const int kk = i / 300;
            const int col = i - kk * 300;
            const int k = k0 + kk;
            Bs[kk * BSTR + col] = (k < K) ? W[(size_t)k * HIDDEN + col] : 0.f;
        }
        for (int i = tid; i < BK * BM; i += 512) {
            const int r  = i >> 4;
            const int kk = i & 15;
            const int k  = k0 + kk;
            float v = 0.f;
            if (MODE == 0 || MODE == 3 || MODE == 4) {
                if (k < K) v = Adense[(size_t)(row0 + r) * lda + k];
            } else { // MODE 2: concat(fatoms[0:136], gather6 fp16 msg [136:436])
                if (k < ATOM_FDIM) {
                    v = Adense[(size_t)(row0 + r) * lda + k];
                } else if (k < K) {
                    const int kc = k - ATOM_FDIM;
                    const __half* mh = (const __half*)msgv;
#pragma unroll
                    for (int j = 0; j < MAX_NB; ++j)
                        v += __half2float(mh[(size_t)gx[r * MAX_NB + j] * HIDDEN + kc]);
                }
            }
            As[kk * ASTR + r] = v;
        }
        __syncthreads();
#pragma unroll
        for (int kk = 0; kk < BK; ++kk) {
            const float4 bq = *(const float4*)&Bs[kk * BSTR + c0];
            const float  b4 = Bs[kk * BSTR + c4];
            const float4 a0 = *(const float4*)&As[kk * ASTR + wave * 8];
            const float4 a1 = *(const float4*)&As[kk * ASTR + wave * 8 + 4];
            const float ar8[8] = {a0.x, a0.y, a0.z, a0.w, a1.x, a1.y, a1.z, a1.w};
#pragma unroll
            for (int r = 0; r < 8; ++r) {
                acc[r][0] = fmaf(ar8[r], bq.x, acc[r][0]);
                acc[r][1] = fmaf(ar8[r], bq.y, acc[r][1]);
                acc[r][2] = fmaf(ar8[r], bq.z, acc[r][2]);
                acc[r][3] = fmaf(ar8[r], bq.w, acc[r][3]);
                acc[r][4] = fmaf(ar8[r], b4,   acc[r][4]);
            }
        }
        __syncthreads();
    }

    if (MODE == 4) {
        const float4 bqv = *(const float4*)&bias[c0];
        const float  b4v = bias[c4];
        float s0 = 0, s1 = 0, s2 = 0, s3 = 0, s4 = 0;
#pragma unroll
        for (int r = 0; r < 8; ++r) {
            s0 += fmaxf(acc[r][0] + bqv.x, 0.f);
            s1 += fmaxf(acc[r][1] + bqv.y, 0.f);
            s2 += fmaxf(acc[r][2] + bqv.z, 0.f);
            s3 += fmaxf(acc[r][3] + bqv.w, 0.f);
            s4 += fmaxf(acc[r][4] + b4v,   0.f);
        }
        float* wsum = Bs;
        *(float4*)&wsum[wave * BSTR + c0] = make_float4(s0, s1, s2, s3);
        if (has4) wsum[wave * BSTR + c4] = s4;
        __syncthreads();
        const int m0 = blockIdx.x * 2;
        for (int t = tid; t < 2 * HIDDEN; t += 512) {
            const int m = t / HIDDEN, col = t - m * HIDDEN;
            const float v = wsum[(4 * m + 0) * BSTR + col] + wsum[(4 * m + 1) * BSTR + col]
                          + wsum[(4 * m + 2) * BSTR + col] + wsum[(4 * m + 3) * BSTR + col]
                          + hsum[(size_t)(m0 + m) * HIDDEN + col];
            out0[(size_t)(m0 + m) * HIDDEN + col] = v * (1.f / 32.f);
        }
        return;
    }

#pragma unroll
    for (int r = 0; r < 8; ++r) {
        const size_t off = (size_t)(row0 + wave * 8 + r) * HIDDEN;
        float4 v = make_float4(acc[r][0], acc[r][1], acc[r][2], acc[r][3]);
        float v4 = acc[r][4];
        if (MODE == 0) {
            __half* o0 = (__half*)out0;
            __half* o1 = (__half*)out1;
            st_h4(&o0[off + c0], v.x, v.y, v.z, v.w);
            if (has4) o0[off + c4] = __float2half(v4);
            st_h4(&o1[off + c0], fmaxf(v.x,0.f), fmaxf(v.y,0.f), fmaxf(v.z,0.f), fmaxf(v.w,0.f));
            if (has4) o1[off + c4] = __float2half(fmaxf(v4, 0.f));
        } else if (MODE == 2) {
            const float4 bb = *(const float4*)&bias[c0];
            float4 rv = make_float4(fmaxf(v.x+bb.x,0.f), fmaxf(v.y+bb.y,0.f),
                                    fmaxf(v.z+bb.z,0.f), fmaxf(v.w+bb.w,0.f));
            *(float4*)&out0[off + c0] = rv;
            if (has4) out0[off + c4] = fmaxf(v4 + bias[c4], 0.f);
        } else { // MODE 3
            *(float4*)&out0[off + c0] = v;
            if (has4) out0[off + c4] = v4;
        }
    }
}

// ---------------------------------------------------------------------------
// Per-molecule middle stage (R6/R7/R8-proven): logits, softmax, P=att@h, hsum.
// ---------------------------------------------------------------------------
#define HSTR 320

__device__ __forceinline__ int hsw(int a, int c4u) {
    return a * HSTR + ((c4u ^ (a & 7)) << 2);
}

__global__ __launch_bounds__(512)
void attn_mid(const float* __restrict__ atom_h,
              const float* __restrict__ q_all,
              float* __restrict__ P_all,
              float* __restrict__ hsum)
{
    __shared__ float hs[APM * HSTR];
    __shared__ float qs[APM * HIDDEN];
    __shared__ float att[APM][33];

    const int tid  = threadIdx.x;
    const int wave = tid >> 6;
    const int lane = tid & 63;
    const int mol  = blockIdx.x;
    const float* hb = atom_h + (size_t)mol * APM * HIDDEN;
    const float* qb = q_all  + (size_t)mol * APM * HIDDEN;

    for (int j = tid; j < APM * 75; j += 512) {
        const int a = j / 75, c4u = j - a * 75;
        *(float4*)&hs[hsw(a, c4u)] = *(const float4*)&hb[(size_t)a * HIDDEN + 4 * c4u];
    }
    for (int j = tid; j < APM * 75; j += 512)
        *(float4*)&qs[4 * j] = *(const float4*)&qb[4 * j];
    __syncthreads();

    {
        const int a = tid >> 5, b = tid & 31;
        float s0 = 0.f, s1 = 0.f;
        for (int t = 0; t < 75; ++t) {
            const float4 hv = *(const float4*)&hs[hsw(b, t)];
            const float4 q0 = *(const float4*)&qs[a * HIDDEN + 4 * t];
            const float4 q1 = *(const float4*)&qs[(a + 16) * HIDDEN + 4 * t];
            s0 = fmaf(q0.x, hv.x, fmaf(q0.y, hv.y, fmaf(q0.z, hv.z, fmaf(q0.w, hv.w, s0))));
            s1 = fmaf(q1.x, hv.x, fmaf(q1.y, hv.y, fmaf(q1.z, hv.z, fmaf(q1.w, hv.w, s1))));
        }
        att[a][b] = s0;
        att[a + 16][b] = s1;
    }
    __syncthreads();

    if (tid < APM) {
        float m = -3.4e38f;
#pragma unroll 4
        for (int b = 0; b < APM; ++b) m = fmaxf(m, att[tid][b]);
        float s = 0.f;
#pragma unroll 4
        for (int b = 0; b < APM; ++b) { const float e = __expf(att[tid][b] - m); att[tid][b] = e; s += e; }
        const float inv = 1.f / s;
#pragma unroll 4
        for (int b = 0; b < APM; ++b) att[tid][b] *= inv;
    }
    __syncthreads();

    {
        const int r0 = wave * 4;
        const int c0 = 4 * lane;
        const bool has4 = (lane < 44);
        const int c4u = 64 + (lane >> 2), c4r = lane & 3;
        float4 p[4];
        float  p4[4];
#pragma unroll
        for (int r = 0; r < 4; ++r) { p[r] = make_float4(0,0,0,0); p4[r] = 0.f; }
#pragma unroll 4
        for (int b = 0; b < APM; ++b) {
            const float4 hv = *(const float4*)&hs[hsw(b, lane)];
            const float  h4 = hs[hsw(b, c4u) + c4r];
#pragma unroll
            for (int r = 0; r < 4; ++r) {
                const float av = att[r0 + r][b];
                p[r].x = fmaf(av, hv.x, p[r].x);
                p[r].y = fmaf(av, hv.y, p[r].y);
                p[r].z = fmaf(av, hv.z, p[r].z);
                p[r].w = fmaf(av, hv.w, p[r].w);
                p4[r]  = fmaf(av, h4,   p4[r]);
            }
        }
#pragma unroll
        for (int r = 0; r < 4; ++r) {
            const size_t off = ((size_t)mol * APM + r0 + r) * HIDDEN;
            *(float4*)&P_all[off + c0] = p[r];
            if (has4) P_all[off + 256 + lane] = p4[r];
        }
    }

    if (tid < HIDDEN) {
        const int c4u = tid >> 2, cr = tid & 3;
        float s = 0.f;
#pragma unroll 4
        for (int a = 0; a < APM; ++a) s += hs[hsw(a, c4u) + cr];
        hsum[(size_t)mol * HIDDEN + tid] = s;
    }
}

// ---------------------------------------------------------------------------
extern "C" void kernel_launch(void* const* d_in, const int* in_sizes, int n_in,
                              void* d_out, int out_size, void* d_ws, size_t ws_size,
                              hipStream_t stream)
{
    const float* fatoms = (const float*)d_in[0];
    const float* fbonds = (const float*)d_in[1];
    const int*   agraph = (const int*)d_in[2];
    const int*   bgraph = (const int*)d_in[3];
    const float* W_i    = (const float*)d_in[4];
    const float* W_h    = (const float*)d_in[5];
    const float* W_o    = (const float*)d_in[6];
    const float* b_o    = (const float*)d_in[7];
    const float* W_a    = (const float*)d_in[8];
    const float* W_b    = (const float*)d_in[9];
    const float* b_b    = (const float*)d_in[10];
    float* out = (float*)d_out;

    const size_t WB = (size_t)N_BONDS * HIDDEN;   // 78,643,200
    const size_t WA = (size_t)N_ATOMS * HIDDEN;   // 39,321,600
    // float-unit layout: binput_h(WB/2) | msgA(WB/2) | msgB(WB/2) | acc_h(WB/2)
    //                  | atom_h(WA) | q_all(WA) | P_all(WA) | hsum | wt
    const size_t need = (2 * WB + 3 * WA + (size_t)N_MOLS * HIDDEN + WT_C * WT_K) * sizeof(float);
    float* base;
    if (ws_size >= need) {
        base = (float*)d_ws;
    } else {
        void* p = nullptr;
        (void)hipGetSymbolAddress(&p, HIP_SYMBOL(g_scratch));
        base = (float*)p;
    }
    __half* binput_h = (__half*)base;
    __half* msgA     = (__half*)(base + WB / 2);
    __half* msgB     = (__half*)(base + WB);
    __half* acc_h    = (__half*)(base + 3 * WB / 2);
    float*  atom_h   = base + 2 * WB;
    float*  q_all    = atom_h + WA;
    float*  P_all    = q_all + WA;
    float*  hsum     = P_all + WA;
    u16*    wt_hi    = (u16*)(hsum + (size_t)N_MOLS * HIDDEN);
    u16*    wt_lo    = wt_hi + WT_C * WT_K;

    const dim3 blk(512);

    // split/transpose W_h once per call
    wt_prep<<<(WT_C * WT_K + 255) / 256, dim3(256), 0, stream>>>(W_h, wt_hi, wt_lo);

    // binput_h = fp16(fbonds @ W_i) ; msgA = fp16(relu(...))
    gemm_fused<0><<<N_BONDS / BM, blk, 0, stream>>>(
        fbonds, BOND_IN, nullptr, nullptr, W_i, nullptr, nullptr,
        (float*)binput_h, (float*)msgA, BOND_IN);

    // 5 message-passing iterations — two K-column-blocked passes each
    const __half* cur = msgA;
    __half* nxt = msgB;
    for (int it = 0; it < 5; ++it) {
        mp_mfma<0><<<N_BONDS / 64, blk, 0, stream>>>(
            cur, bgraph, wt_hi, wt_lo, binput_h, acc_h, nullptr, 0);
        mp_mfma<1><<<N_BONDS / 64, blk, 0, stream>>>(
            cur, bgraph, wt_hi, wt_lo, binput_h, acc_h, nxt, 160);
        __half* t = nxt; nxt = (__half*)cur; cur = t;
    }
    // final message in cur

    // atom_h = relu(concat(fatoms, gather6(fp16 msg)) @ W_o + b_o)
    gemm_fused<2><<<N_ATOMS / BM, blk, 0, stream>>>(
        fatoms, ATOM_FDIM, (const void*)cur, agraph, W_o, b_o, nullptr,
        atom_h, nullptr, ATOM_FDIM + HIDDEN);

    // q_all = atom_h @ W_a
    gemm_fused<3><<<N_ATOMS / BM, blk, 0, stream>>>(
        atom_h, HIDDEN, nullptr, nullptr, W_a, nullptr, nullptr,
        q_all, nullptr, HIDDEN);

    // per-molecule: logits, softmax, P = att@h, hsum
    attn_mid<<<N_MOLS, dim3(512), 0, stream>>>(atom_h, q_all, P_all, hsum);

    // out[mol] = (hsum + sum_rows relu(P @ W_b + b_b)) / 32
    gemm_fused<4><<<N_ATOMS / BM, blk, 0, stream>>>(
        P_all, HIDDEN, nullptr, nullptr, W_b, b_b, hsum,
        out, nullptr, HIDDEN);
}

// Round 14
// 6710.617 us; speedup vs baseline: 1.1738x; 1.1738x over previous
//
#include <hip/hip_runtime.h>
#include <hip/hip_fp16.h>
#include <math.h>

#define HIDDEN 300
#define ATOM_FDIM 136
#define BOND_IN 148
#define MAX_NB 6
#define N_MOLS 4096
#define APM 32
#define N_ATOMS (N_MOLS*APM)
#define N_BONDS (2*N_ATOMS)

#define BK 16
#define BM 64
#define ASTR 68     // fp32-GEMM A-tile row stride (words)
#define BSTR 304    // fp32-GEMM B-tile row stride (words)

// Wt (split-bf16, transposed) geometry: [304 cols][K] per split
#define WT_C 304
#define WTK_H 320   // W_h: K=300 padded
#define WTK_O 448   // W_o: K=436 padded

typedef unsigned short u16;
typedef short bf16x8 __attribute__((ext_vector_type(8)));
typedef float f32x4  __attribute__((ext_vector_type(4)));

// Fallback scratch if ws_size too small (float count of the layout below).
__device__ float g_scratch[3ull * N_BONDS * HIDDEN / 2 + 3ull * N_ATOMS * HIDDEN
                           + (size_t)N_MOLS * HIDDEN + WT_C * (WTK_H + WTK_O)];

__device__ __forceinline__ u16 bf16_rne(float x) {
    unsigned u = __float_as_uint(x);
    unsigned r = (u + 0x7fffu + ((u >> 16) & 1u)) >> 16;
    return (u16)r;
}
__device__ __forceinline__ float bf16_f(u16 h) {
    return __uint_as_float(((unsigned)h) << 16);
}
__device__ __forceinline__ void st_h4(__half* p, float a, float b, float c, float d) {
    *(__half2*)(p)     = __floats2half2_rn(a, b);
    *(__half2*)(p + 2) = __floats2half2_rn(c, d);
}

// ---------------------------------------------------------------------------
// Prep: hi/lo[col][k] = split-bf16 of W[k][col], zero-padded to [WT_C][wtk]
// ---------------------------------------------------------------------------
__global__ __launch_bounds__(256)
void wt_prep(const float* __restrict__ W, u16* __restrict__ hi_out,
             u16* __restrict__ lo_out, int kact, int wtk)
{
    const int i = blockIdx.x * 256 + threadIdx.x;
    if (i >= WT_C * wtk) return;
    const int c = i / wtk, k = i - c * wtk;
    float w = (c < HIDDEN && k < kact) ? W[(size_t)k * HIDDEN + c] : 0.f;
    const u16 hi = bf16_rne(w);
    const u16 lo = bf16_rne(w - bf16_f(hi));
    hi_out[i] = hi;
    lo_out[i] = lo;
}

// ---------------------------------------------------------------------------
// Message-passing step via MFMA — RESTORED R7-submission structure (measured
// 915 us in Round 8; best of 4 variants). Per-K-step stage/MFMA alternation.
//   out0 = fp16( relu(binput + gather6(msg) @ W_h) )
// D map (m89): col = lane&15, row = (lane>>4)*4 + j.
// ---------------------------------------------------------------------------
__global__ __launch_bounds__(512)
void mp_mfma(const __half* __restrict__ msg,
             const int*   __restrict__ graph,
             const u16*   __restrict__ wt_hi,
             const u16*   __restrict__ wt_lo,
             const __half* __restrict__ binput,
             __half* __restrict__ out0)
{
    __shared__ u16 Ahi[64 * 40];
    __shared__ u16 Alo[64 * 40];
    __shared__ int gx[64 * MAX_NB];

    const int tid  = threadIdx.x;
    const int row0 = blockIdx.x * 64;

    if (tid < 64 * MAX_NB) gx[tid] = graph[(size_t)row0 * MAX_NB + tid];
    __syncthreads();

    const int w  = tid >> 6;
    const int l  = tid & 63;
    const int g  = l >> 4;
    const int mr = (w & 3) * 16 + (l & 15);
    const int tbase = (w >> 2) ? 10 : 0;
    const int ntile = (w >> 2) ? 9 : 10;

    const int sr = tid >> 3;
    const int sk = (tid & 7) * 4;
    const int* sg = &gx[sr * MAX_NB];

    f32x4 acc[10];
#pragma unroll
    for (int t = 0; t < 10; ++t) acc[t] = (f32x4){0.f, 0.f, 0.f, 0.f};

    for (int k0 = 0; k0 < HIDDEN; k0 += 32) {
        // ---- stage A: fp16 gather -> fp32 sum -> split bf16 hi/lo
        // (k>=300 reads run past the row into adjacent scratch: finite values,
        //  and Wt is zero there, so products vanish — proven-safe R7/R8)
        const int kk = k0 + sk;
        float s0 = 0.f, s1 = 0.f, s2 = 0.f, s3 = 0.f;
#pragma unroll
        for (int j = 0; j < MAX_NB; ++j) {
            const __half2* p = (const __half2*)(msg + (size_t)sg[j] * HIDDEN + kk);
            const float2 u = __half22float2(p[0]);
            const float2 v = __half22float2(p[1]);
            s0 += u.x; s1 += u.y; s2 += v.x; s3 += v.y;
        }
        const u16 h0 = bf16_rne(s0), h1 = bf16_rne(s1), h2 = bf16_rne(s2), h3 = bf16_rne(s3);
        const u16 e0 = bf16_rne(s0 - bf16_f(h0)), e1 = bf16_rne(s1 - bf16_f(h1));
        const u16 e2 = bf16_rne(s2 - bf16_f(h2)), e3 = bf16_rne(s3 - bf16_f(h3));
        uint2 ph, pl;
        ph.x = (unsigned)h0 | ((unsigned)h1 << 16);
        ph.y = (unsigned)h2 | ((unsigned)h3 << 16);
        pl.x = (unsigned)e0 | ((unsigned)e1 << 16);
        pl.y = (unsigned)e2 | ((unsigned)e3 << 16);
        *(uint2*)&Ahi[sr * 40 + sk] = ph;
        *(uint2*)&Alo[sr * 40 + sk] = pl;
        __syncthreads();

        const bf16x8 ahi = *(const bf16x8*)&Ahi[mr * 40 + 8 * g];
        const bf16x8 alo = *(const bf16x8*)&Alo[mr * 40 + 8 * g];
        const int kb = k0 + 8 * g;

#pragma unroll
        for (int t = 0; t < 10; ++t) {
            if (t < ntile) {
                const int cn = 16 * (tbase + t) + (l & 15);
                const bf16x8 bhi = *(const bf16x8*)&wt_hi[(size_t)cn * WTK_H + kb];
                const bf16x8 blo = *(const bf16x8*)&wt_lo[(size_t)cn * WTK_H + kb];
                acc[t] = __builtin_amdgcn_mfma_f32_16x16x32_bf16(ahi, bhi, acc[t], 0, 0, 0);
                acc[t] = __builtin_amdgcn_mfma_f32_16x16x32_bf16(ahi, blo, acc[t], 0, 0, 0);
                acc[t] = __builtin_amdgcn_mfma_f32_16x16x32_bf16(alo, bhi, acc[t], 0, 0, 0);
            }
        }
        __syncthreads();
    }

    // ---- epilogue: D[row=(l>>4)*4+j][col=l&15] per tile
#pragma unroll
    for (int t = 0; t < 10; ++t) {
        if (t < ntile) {
            const int col = 16 * (tbase + t) + (l & 15);
            if (col < HIDDEN) {
#pragma unroll
                for (int j = 0; j < 4; ++j) {
                    const size_t off = (size_t)(row0 + (w & 3) * 16 + 4 * g + j) * HIDDEN + col;
                    out0[off] = __float2half(fmaxf(__half2float(binput[off]) + acc[t][j], 0.f));
                }
            }
        }
    }
}

// ---------------------------------------------------------------------------
// NEW: atom-hidden stage via MFMA (replaces scalar mode-2, 870 us @ VALU 63%):
//   atom_h = relu( concat(fatoms, gather6(msg, agraph)) @ W_o + b_o )   [fp32]
// Same proven template; K = 448 (436 padded). Chunks with k+4<=136 read
// fatoms (float4); chunks with k>=136 do the 6x uint2 fp16 gather (136%4==0
// so no chunk straddles). Gather tail past k=436 reads finite data x zero Wt.
// ---------------------------------------------------------------------------
__global__ __launch_bounds__(512)
void mo_mfma(const float* __restrict__ fatoms,
             const __half* __restrict__ msg,
             const int*   __restrict__ graph,
             const u16*   __restrict__ wto_hi,
             const u16*   __restrict__ wto_lo,
             const float* __restrict__ bias,
             float* __restrict__ out0)
{
    __shared__ u16 Ahi[64 * 40];
    __shared__ u16 Alo[64 * 40];
    __shared__ int gx[64 * MAX_NB];

    const int tid  = threadIdx.x;
    const int row0 = blockIdx.x * 64;

    if (tid < 64 * MAX_NB) gx[tid] = graph[(size_t)row0 * MAX_NB + tid];
    __syncthreads();

    const int w  = tid >> 6;
    const int l  = tid & 63;
    const int g  = l >> 4;
    const int mr = (w & 3) * 16 + (l & 15);
    const int tbase = (w >> 2) ? 10 : 0;
    const int ntile = (w >> 2) ? 9 : 10;

    const int sr = tid >> 3;
    const int sk = (tid & 7) * 4;
    const int* sg = &gx[sr * MAX_NB];
    const float* fa = fatoms + (size_t)(row0 + sr) * ATOM_FDIM;

    f32x4 acc[10];
#pragma unroll
    for (int t = 0; t < 10; ++t) acc[t] = (f32x4){0.f, 0.f, 0.f, 0.f};

    for (int k0 = 0; k0 < WTK_O; k0 += 32) {
        const int kk = k0 + sk;
        float s0, s1, s2, s3;
        if (kk + 4 <= ATOM_FDIM) {
            const float4 v = *(const float4*)&fa[kk];
            s0 = v.x; s1 = v.y; s2 = v.z; s3 = v.w;
        } else {
            const int kg = kk - ATOM_FDIM;   // >= 0 (no straddle: 136 % 4 == 0)
            s0 = 0.f; s1 = 0.f; s2 = 0.f; s3 = 0.f;
#pragma unroll
            for (int j = 0; j < MAX_NB; ++j) {
                const __half2* p = (const __half2*)(msg + (size_t)sg[j] * HIDDEN + kg);
                const float2 u = __half22float2(p[0]);
                const float2 v = __half22float2(p[1]);
                s0 += u.x; s1 += u.y; s2 += v.x; s3 += v.y;
            }
        }
        const u16 h0 = bf16_rne(s0), h1 = bf16_rne(s1), h2 = bf16_rne(s2), h3 = bf16_rne(s3);
        const u16 e0 = bf16_rne(s0 - bf16_f(h0)), e1 = bf16_rne(s1 - bf16_f(h1));
        const u16 e2 = bf16_rne(s2 - bf16_f(h2)), e3 = bf16_rne(s3 - bf16_f(h3));
        uint2 ph, pl;
        ph.x = (unsigned)h0 | ((unsigned)h1 << 16);
        ph.y = (unsigned)h2 | ((unsigned)h3 << 16);
        pl.x = (unsigned)e0 | ((unsigned)e1 << 16);
        pl.y = (unsigned)e2 | ((unsigned)e3 << 16);
        *(uint2*)&Ahi[sr * 40 + sk] = ph;
        *(uint2*)&Alo[sr * 40 + sk] = pl;
        __syncthreads();

        const bf16x8 ahi = *(const bf16x8*)&Ahi[mr * 40 + 8 * g];
        const bf16x8 alo = *(const bf16x8*)&Alo[mr * 40 + 8 * g];
        const int kb = k0 + 8 * g;

#pragma unroll
        for (int t = 0; t < 10; ++t) {
            if (t < ntile) {
                const int cn = 16 * (tbase + t) + (l & 15);
                const bf16x8 bhi = *(const bf16x8*)&wto_hi[(size_t)cn * WTK_O + kb];
                const bf16x8 blo = *(const bf16x8*)&wto_lo[(size_t)cn * WTK_O + kb];
                acc[t] = __builtin_amdgcn_mfma_f32_16x16x32_bf16(ahi, bhi, acc[t], 0, 0, 0);
                acc[t] = __builtin_amdgcn_mfma_f32_16x16x32_bf16(ahi, blo, acc[t], 0, 0, 0);
                acc[t] = __builtin_amdgcn_mfma_f32_16x16x32_bf16(alo, bhi, acc[t], 0, 0, 0);
            }
        }
        __syncthreads();
    }

    // ---- epilogue: fp32 atom_h = relu(acc + bias)
#pragma unroll
    for (int t = 0; t < 10; ++t) {
        if (t < ntile) {
            const int col = 16 * (tbase + t) + (l & 15);
            if (col < HIDDEN) {
                const float bv = bias[col];
#pragma unroll
                for (int j = 0; j < 4; ++j) {
                    const size_t off = (size_t)(row0 + (w & 3) * 16 + 4 * g + j) * HIDDEN + col;
                    out0[off] = fmaxf(acc[t][j] + bv, 0.f);
                }
            }
        }
    }
}

// ---------------------------------------------------------------------------
// fp32 fused GEMM family (proven skeleton). 512 threads, BM=64, BK=16.
//  MODE 0: A=fbonds[lda] -> out0=fp16(A@W), out1=fp16(relu(A@W))
//  MODE 3: A dense [lda] -> out0=A@W
//  MODE 4: A dense (P_all) -> out0[mol]=(hsum+sum_rows relu(A@W+bias))/32
// ---------------------------------------------------------------------------
template<int MODE>
__global__ __launch_bounds__(512)
void gemm_fused(const float* __restrict__ Adense, int lda,
                const float* __restrict__ W,
                const float* __restrict__ bias,
                const float* __restrict__ hsum,
                float* __restrict__ out0,
                float* __restrict__ out1,
                int K)
{
    __shared__ float As[BK * ASTR];
    __shared__ float Bs[BK * BSTR];

    const int tid  = threadIdx.x;
    const int wave = tid >> 6;
    const int lane = tid & 63;
    const int row0 = blockIdx.x * BM;
    const int c0   = 4 * lane;
    const bool has4 = (lane < HIDDEN - 256);
    const int  c4   = has4 ? (256 + lane) : 256;

    float acc[8][5];
#pragma unroll
    for (int r = 0; r < 8; ++r)
#pragma unroll
        for (int c = 0; c < 5; ++c) acc[r][c] = 0.f;

    const int nk = (K + BK - 1) / BK;
    for (int kt = 0; kt < nk; ++kt) {
        const int k0 = kt * BK;
        for (int i = tid; i < BK * 300; i += 512) {
            const int kk = i / 300;
            const int col = i - kk * 300;
            const int k = k0 + kk;
            Bs[kk * BSTR + col] = (k < K) ? W[(size_t)k * HIDDEN + col] : 0.f;
        }
        for (int i = tid; i < BK * BM; i += 512) {
            const int r  = i >> 4;
            const int kk = i & 15;
            const int k  = k0 + kk;
            As[kk * ASTR + r] = (k < K) ? Adense[(size_t)(row0 + r) * lda + k] : 0.f;
        }
        __syncthreads();
#pragma unroll
        for (int kk = 0; kk < BK; ++kk) {
            const float4 bq = *(const float4*)&Bs[kk * BSTR + c0];
            const float  b4 = Bs[kk * BSTR + c4];
            const float4 a0 = *(const float4*)&As[kk * ASTR + wave * 8];
            const float4 a1 = *(const float4*)&As[kk * ASTR + wave * 8 + 4];
            const float ar8[8] = {a0.x, a0.y, a0.z, a0.w, a1.x, a1.y, a1.z, a1.w};
#pragma unroll
            for (int r = 0; r < 8; ++r) {
                acc[r][0] = fmaf(ar8[r], bq.x, acc[r][0]);
                acc[r][1] = fmaf(ar8[r], bq.y, acc[r][1]);
                acc[r][2] = fmaf(ar8[r], bq.z, acc[r][2]);
                acc[r][3] = fmaf(ar8[r], bq.w, acc[r][3]);
                acc[r][4] = fmaf(ar8[r], b4,   acc[r][4]);
            }
        }
        __syncthreads();
    }

    if (MODE == 4) {
        const float4 bqv = *(const float4*)&bias[c0];
        const float  b4v = bias[c4];
        float s0 = 0, s1 = 0, s2 = 0, s3 = 0, s4 = 0;
#pragma unroll
        for (int r = 0; r < 8; ++r) {
            s0 += fmaxf(acc[r][0] + bqv.x, 0.f);
            s1 += fmaxf(acc[r][1] + bqv.y, 0.f);
            s2 += fmaxf(acc[r][2] + bqv.z, 0.f);
            s3 += fmaxf(acc[r][3] + bqv.w, 0.f);
            s4 += fmaxf(acc[r][4] + b4v,   0.f);
        }
        float* wsum = Bs;
        *(float4*)&wsum[wave * BSTR + c0] = make_float4(s0, s1, s2, s3);
        if (has4) wsum[wave * BSTR + c4] = s4;
        __syncthreads();
        const int m0 = blockIdx.x * 2;
        for (int t = tid; t < 2 * HIDDEN; t += 512) {
            const int m = t / HIDDEN, col = t - m * HIDDEN;
            const float v = wsum[(4 * m + 0) * BSTR + col] + wsum[(4 * m + 1) * BSTR + col]
                          + wsum[(4 * m + 2) * BSTR + col] + wsum[(4 * m + 3) * BSTR + col]
                          + hsum[(size_t)(m0 + m) * HIDDEN + col];
            out0[(size_t)(m0 + m) * HIDDEN + col] = v * (1.f / 32.f);
        }
        return;
    }

#pragma unroll
    for (int r = 0; r < 8; ++r) {
        const size_t off = (size_t)(row0 + wave * 8 + r) * HIDDEN;
        float4 v = make_float4(acc[r][0], acc[r][1], acc[r][2], acc[r][3]);
        float v4 = acc[r][4];
        if (MODE == 0) {
            __half* o0 = (__half*)out0;
            __half* o1 = (__half*)out1;
            st_h4(&o0[off + c0], v.x, v.y, v.z, v.w);
            if (has4) o0[off + c4] = __float2half(v4);
            st_h4(&o1[off + c0], fmaxf(v.x,0.f), fmaxf(v.y,0.f), fmaxf(v.z,0.f), fmaxf(v.w,0.f));
            if (has4) o1[off + c4] = __float2half(fmaxf(v4, 0.f));
        } else { // MODE 3
            *(float4*)&out0[off + c0] = v;
            if (has4) out0[off + c4] = v4;
        }
    }
}

// ---------------------------------------------------------------------------
// Per-molecule middle stage (proven): logits, softmax, P=att@h, hsum.
// ---------------------------------------------------------------------------
#define HSTR 320

__device__ __forceinline__ int hsw(int a, int c4u) {
    return a * HSTR + ((c4u ^ (a & 7)) << 2);
}

__global__ __launch_bounds__(512)
void attn_mid(const float* __restrict__ atom_h,
              const float* __restrict__ q_all,
              float* __restrict__ P_all,
              float* __restrict__ hsum)
{
    __shared__ float hs[APM * HSTR];
    __shared__ float qs[APM * HIDDEN];
    __shared__ float att[APM][33];

    const int tid  = threadIdx.x;
    const int wave = tid >> 6;
    const int lane = tid & 63;
    const int mol  = blockIdx.x;
    const float* hb = atom_h + (size_t)mol * APM * HIDDEN;
    const float* qb = q_all  + (size_t)mol * APM * HIDDEN;

    for (int j = tid; j < APM * 75; j += 512) {
        const int a = j / 75, c4u = j - a * 75;
        *(float4*)&hs[hsw(a, c4u)] = *(const float4*)&hb[(size_t)a * HIDDEN + 4 * c4u];
    }
    for (int j = tid; j < APM * 75; j += 512)
        *(float4*)&qs[4 * j] = *(const float4*)&qb[4 * j];
    __syncthreads();

    {
        const int a = tid >> 5, b = tid & 31;
        float s0 = 0.f, s1 = 0.f;
        for (int t = 0; t < 75; ++t) {
            const float4 hv = *(const float4*)&hs[hsw(b, t)];
            const float4 q0 = *(const float4*)&qs[a * HIDDEN + 4 * t];
            const float4 q1 = *(const float4*)&qs[(a + 16) * HIDDEN + 4 * t];
            s0 = fmaf(q0.x, hv.x, fmaf(q0.y, hv.y, fmaf(q0.z, hv.z, fmaf(q0.w, hv.w, s0))));
            s1 = fmaf(q1.x, hv.x, fmaf(q1.y, hv.y, fmaf(q1.z, hv.z, fmaf(q1.w, hv.w, s1))));
        }
        att[a][b] = s0;
        att[a + 16][b] = s1;
    }
    __syncthreads();

    if (tid < APM) {
        float m = -3.4e38f;
#pragma unroll 4
        for (int b = 0; b < APM; ++b) m = fmaxf(m, att[tid][b]);
        float s = 0.f;
#pragma unroll 4
        for (int b = 0; b < APM; ++b) { const float e = __expf(att[tid][b] - m); att[tid][b] = e; s += e; }
        const float inv = 1.f / s;
#pragma unroll 4
        for (int b = 0; b < APM; ++b) att[tid][b] *= inv;
    }
    __syncthreads();

    {
        const int r0 = wave * 4;
        const int c0 = 4 * lane;
        const bool has4 = (lane < 44);
        const int c4u = 64 + (lane >> 2), c4r = lane & 3;
        float4 p[4];
        float  p4[4];
#pragma unroll
        for (int r = 0; r < 4; ++r) { p[r] = make_float4(0,0,0,0); p4[r] = 0.f; }
#pragma unroll 4
        for (int b = 0; b < APM; ++b) {
            const float4 hv = *(const float4*)&hs[hsw(b, lane)];
            const float  h4 = hs[hsw(b, c4u) + c4r];
#pragma unroll
            for (int r = 0; r < 4; ++r) {
                const float av = att[r0 + r][b];
                p[r].x = fmaf(av, hv.x, p[r].x);
                p[r].y = fmaf(av, hv.y, p[r].y);
                p[r].z = fmaf(av, hv.z, p[r].z);
                p[r].w = fmaf(av, hv.w, p[r].w);
                p4[r]  = fmaf(av, h4,   p4[r]);
            }
        }
#pragma unroll
        for (int r = 0; r < 4; ++r) {
            const size_t off = ((size_t)mol * APM + r0 + r) * HIDDEN;
            *(float4*)&P_all[off + c0] = p[r];
            if (has4) P_all[off + 256 + lane] = p4[r];
        }
    }

    if (tid < HIDDEN) {
        const int c4u = tid >> 2, cr = tid & 3;
        float s = 0.f;
#pragma unroll 4
        for (int a = 0; a < APM; ++a) s += hs[hsw(a, c4u) + cr];
        hsum[(size_t)mol * HIDDEN + tid] = s;
    }
}

// ---------------------------------------------------------------------------
extern "C" void kernel_launch(void* const* d_in, const int* in_sizes, int n_in,
                              void* d_out, int out_size, void* d_ws, size_t ws_size,
                              hipStream_t stream)
{
    const float* fatoms = (const float*)d_in[0];
    const float* fbonds = (const float*)d_in[1];
    const int*   agraph = (const int*)d_in[2];
    const int*   bgraph = (const int*)d_in[3];
    const float* W_i    = (const float*)d_in[4];
    const float* W_h    = (const float*)d_in[5];
    const float* W_o    = (const float*)d_in[6];
    const float* b_o    = (const float*)d_in[7];
    const float* W_a    = (const float*)d_in[8];
    const float* W_b    = (const float*)d_in[9];
    const float* b_b    = (const float*)d_in[10];
    float* out = (float*)d_out;

    const size_t WB = (size_t)N_BONDS * HIDDEN;   // 78,643,200
    const size_t WA = (size_t)N_ATOMS * HIDDEN;   // 39,321,600
    // float-unit layout: binput_h(WB/2) | msgA(WB/2) | msgB(WB/2) |
    //   atom_h(WA) | q_all(WA) | P_all(WA) | hsum | wt_h(hi+lo) | wt_o(hi+lo)
    const size_t need = (3 * WB / 2 + 3 * WA + (size_t)N_MOLS * HIDDEN
                         + WT_C * (WTK_H + WTK_O)) * sizeof(float);
    float* base;
    if (ws_size >= need) {
        base = (float*)d_ws;
    } else {
        void* p = nullptr;
        (void)hipGetSymbolAddress(&p, HIP_SYMBOL(g_scratch));
        base = (float*)p;
    }
    __half* binput_h = (__half*)base;
    __half* msgA     = (__half*)(base + WB / 2);
    __half* msgB     = (__half*)(base + WB);
    float*  atom_h   = base + 3 * WB / 2;
    float*  q_all    = atom_h + WA;
    float*  P_all    = q_all + WA;
    float*  hsum     = P_all + WA;
    u16*    wt_hi    = (u16*)(hsum + (size_t)N_MOLS * HIDDEN);
    u16*    wt_lo    = wt_hi + WT_C * WTK_H;
    u16*    wto_hi   = wt_lo + WT_C * WTK_H;
    u16*    wto_lo   = wto_hi + WT_C * WTK_O;

    const dim3 blk(512);

    // split/transpose W_h and W_o once per call
    wt_prep<<<(WT_C * WTK_H + 255) / 256, dim3(256), 0, stream>>>(
        W_h, wt_hi, wt_lo, HIDDEN, WTK_H);
    wt_prep<<<(WT_C * WTK_O + 255) / 256, dim3(256), 0, stream>>>(
        W_o, wto_hi, wto_lo, ATOM_FDIM + HIDDEN, WTK_O);

    // binput_h = fp16(fbonds @ W_i) ; msgA = fp16(relu(...))
    gemm_fused<0><<<N_BONDS / BM, blk, 0, stream>>>(
        fbonds, BOND_IN, W_i, nullptr, nullptr,
        (float*)binput_h, (float*)msgA, BOND_IN);

    // 5 message-passing iterations — restored R7-submission MFMA kernel
    const __half* cur = msgA;
    __half* nxt = msgB;
    for (int it = 0; it < 5; ++it) {
        mp_mfma<<<N_BONDS / 64, blk, 0, stream>>>(
            cur, bgraph, wt_hi, wt_lo, binput_h, nxt);
        __half* t = nxt; nxt = (__half*)cur; cur = t;
    }
    // final message in cur

    // atom_h = relu(concat(fatoms, gather6(msg)) @ W_o + b_o) — MFMA port
    mo_mfma<<<N_ATOMS / 64, blk, 0, stream>>>(
        fatoms, cur, agraph, wto_hi, wto_lo, b_o, atom_h);

    // q_all = atom_h @ W_a
    gemm_fused<3><<<N_ATOMS / BM, blk, 0, stream>>>(
        atom_h, HIDDEN, W_a, nullptr, nullptr,
        q_all, nullptr, HIDDEN);

    // per-molecule: logits, softmax, P = att@h, hsum
    attn_mid<<<N_MOLS, dim3(512), 0, stream>>>(atom_h, q_all, P_all, hsum);

    // out[mol] = (hsum + sum_rows relu(P @ W_b + b_b)) / 32
    gemm_fused<4><<<N_ATOMS / BM, blk, 0, stream>>>(
        P_all, HIDDEN, W_b, b_b, hsum,
        out, nullptr, HIDDEN);
}

// Round 15
// 6259.647 us; speedup vs baseline: 1.2583x; 1.0720x over previous
//
#include <hip/hip_runtime.h>
#include <hip/hip_fp16.h>
#include <math.h>

#define HIDDEN 300
#define ATOM_FDIM 136
#define BOND_IN 148
#define MAX_NB 6
#define N_MOLS 4096
#define APM 32
#define N_ATOMS (N_MOLS*APM)
#define N_BONDS (2*N_ATOMS)

// Wt (split-bf16, transposed) geometry: [304 cols][K padded] per split
#define WT_C 304
#define WTK_H 320   // W_h / W_a / W_b: K=300 padded
#define WTK_O 448   // W_o: K=436 padded
#define WTK_I 160   // W_i: K=148 padded

typedef unsigned short u16;
typedef short bf16x8 __attribute__((ext_vector_type(8)));
typedef float f32x4  __attribute__((ext_vector_type(4)));

// Fallback scratch if ws_size too small (float count of the layout below).
// wt region u16 count: 2*304*(320+448+160+320+320) = 953,344 -> 476,672 floats
__device__ float g_scratch[3ull * N_BONDS * HIDDEN / 2 + 3ull * N_ATOMS * HIDDEN
                           + (size_t)N_MOLS * HIDDEN + 476672];

__device__ __forceinline__ u16 bf16_rne(float x) {
    unsigned u = __float_as_uint(x);
    unsigned r = (u + 0x7fffu + ((u >> 16) & 1u)) >> 16;
    return (u16)r;
}
__device__ __forceinline__ float bf16_f(u16 h) {
    return __uint_as_float(((unsigned)h) << 16);
}

// ---------------------------------------------------------------------------
// Prep: hi/lo[col][k] = split-bf16 of W[k][col], zero-padded to [WT_C][wtk]
// ---------------------------------------------------------------------------
__global__ __launch_bounds__(256)
void wt_prep(const float* __restrict__ W, u16* __restrict__ hi_out,
             u16* __restrict__ lo_out, int kact, int wtk)
{
    const int i = blockIdx.x * 256 + threadIdx.x;
    if (i >= WT_C * wtk) return;
    const int c = i / wtk, k = i - c * wtk;
    float w = (c < HIDDEN && k < kact) ? W[(size_t)k * HIDDEN + c] : 0.f;
    const u16 hi = bf16_rne(w);
    const u16 lo = bf16_rne(w - bf16_f(hi));
    hi_out[i] = hi;
    lo_out[i] = lo;
}

// ---------------------------------------------------------------------------
// Shared split helper: fp32 x4 -> packed bf16 hi/lo
// ---------------------------------------------------------------------------
__device__ __forceinline__ void split4(float s0, float s1, float s2, float s3,
                                       uint2& ph, uint2& pl)
{
    const u16 h0 = bf16_rne(s0), h1 = bf16_rne(s1), h2 = bf16_rne(s2), h3 = bf16_rne(s3);
    const u16 e0 = bf16_rne(s0 - bf16_f(h0)), e1 = bf16_rne(s1 - bf16_f(h1));
    const u16 e2 = bf16_rne(s2 - bf16_f(h2)), e3 = bf16_rne(s3 - bf16_f(h3));
    ph.x = (unsigned)h0 | ((unsigned)h1 << 16);
    ph.y = (unsigned)h2 | ((unsigned)h3 << 16);
    pl.x = (unsigned)e0 | ((unsigned)e1 << 16);
    pl.y = (unsigned)e2 | ((unsigned)e3 << 16);
}

// ---------------------------------------------------------------------------
// Message-passing step via MFMA (R14-proven, 915 us): per-K-step alternation.
//   out0 = fp16( relu(binput + gather6(msg) @ W_h) )
// D map (m89): col = lane&15, row = (lane>>4)*4 + j.
// ---------------------------------------------------------------------------
__global__ __launch_bounds__(512)
void mp_mfma(const __half* __restrict__ msg,
             const int*   __restrict__ graph,
             const u16*   __restrict__ wt_hi,
             const u16*   __restrict__ wt_lo,
             const __half* __restrict__ binput,
             __half* __restrict__ out0)
{
    __shared__ u16 Ahi[64 * 40];
    __shared__ u16 Alo[64 * 40];
    __shared__ int gx[64 * MAX_NB];

    const int tid  = threadIdx.x;
    const int row0 = blockIdx.x * 64;

    if (tid < 64 * MAX_NB) gx[tid] = graph[(size_t)row0 * MAX_NB + tid];
    __syncthreads();

    const int w  = tid >> 6;
    const int l  = tid & 63;
    const int g  = l >> 4;
    const int mr = (w & 3) * 16 + (l & 15);
    const int tbase = (w >> 2) ? 10 : 0;
    const int ntile = (w >> 2) ? 9 : 10;

    const int sr = tid >> 3;
    const int sk = (tid & 7) * 4;
    const int* sg = &gx[sr * MAX_NB];

    f32x4 acc[10];
#pragma unroll
    for (int t = 0; t < 10; ++t) acc[t] = (f32x4){0.f, 0.f, 0.f, 0.f};

    for (int k0 = 0; k0 < HIDDEN; k0 += 32) {
        // stage A: fp16 gather -> fp32 sum -> split bf16 (tail reads past row
        // end hit finite data x zero-padded Wt -> products vanish; proven R7/R8)
        const int kk = k0 + sk;
        float s0 = 0.f, s1 = 0.f, s2 = 0.f, s3 = 0.f;
#pragma unroll
        for (int j = 0; j < MAX_NB; ++j) {
            const __half2* p = (const __half2*)(msg + (size_t)sg[j] * HIDDEN + kk);
            const float2 u = __half22float2(p[0]);
            const float2 v = __half22float2(p[1]);
            s0 += u.x; s1 += u.y; s2 += v.x; s3 += v.y;
        }
        uint2 ph, pl;
        split4(s0, s1, s2, s3, ph, pl);
        *(uint2*)&Ahi[sr * 40 + sk] = ph;
        *(uint2*)&Alo[sr * 40 + sk] = pl;
        __syncthreads();

        const bf16x8 ahi = *(const bf16x8*)&Ahi[mr * 40 + 8 * g];
        const bf16x8 alo = *(const bf16x8*)&Alo[mr * 40 + 8 * g];
        const int kb = k0 + 8 * g;

#pragma unroll
        for (int t = 0; t < 10; ++t) {
            if (t < ntile) {
                const int cn = 16 * (tbase + t) + (l & 15);
                const bf16x8 bhi = *(const bf16x8*)&wt_hi[(size_t)cn * WTK_H + kb];
                const bf16x8 blo = *(const bf16x8*)&wt_lo[(size_t)cn * WTK_H + kb];
                acc[t] = __builtin_amdgcn_mfma_f32_16x16x32_bf16(ahi, bhi, acc[t], 0, 0, 0);
                acc[t] = __builtin_amdgcn_mfma_f32_16x16x32_bf16(ahi, blo, acc[t], 0, 0, 0);
                acc[t] = __builtin_amdgcn_mfma_f32_16x16x32_bf16(alo, bhi, acc[t], 0, 0, 0);
            }
        }
        __syncthreads();
    }

#pragma unroll
    for (int t = 0; t < 10; ++t) {
        if (t < ntile) {
            const int col = 16 * (tbase + t) + (l & 15);
            if (col < HIDDEN) {
#pragma unroll
                for (int j = 0; j < 4; ++j) {
                    const size_t off = (size_t)(row0 + (w & 3) * 16 + 4 * g + j) * HIDDEN + col;
                    out0[off] = __float2half(fmaxf(__half2float(binput[off]) + acc[t][j], 0.f));
                }
            }
        }
    }
}

// ---------------------------------------------------------------------------
// Atom-hidden stage via MFMA (R14-proven):
//   atom_h = relu( concat(fatoms, gather6(msg, agraph)) @ W_o + b_o )  [fp32]
// ---------------------------------------------------------------------------
__global__ __launch_bounds__(512)
void mo_mfma(const float* __restrict__ fatoms,
             const __half* __restrict__ msg,
             const int*   __restrict__ graph,
             const u16*   __restrict__ wto_hi,
             const u16*   __restrict__ wto_lo,
             const float* __restrict__ bias,
             float* __restrict__ out0)
{
    __shared__ u16 Ahi[64 * 40];
    __shared__ u16 Alo[64 * 40];
    __shared__ int gx[64 * MAX_NB];

    const int tid  = threadIdx.x;
    const int row0 = blockIdx.x * 64;

    if (tid < 64 * MAX_NB) gx[tid] = graph[(size_t)row0 * MAX_NB + tid];
    __syncthreads();

    const int w  = tid >> 6;
    const int l  = tid & 63;
    const int g  = l >> 4;
    const int mr = (w & 3) * 16 + (l & 15);
    const int tbase = (w >> 2) ? 10 : 0;
    const int ntile = (w >> 2) ? 9 : 10;

    const int sr = tid >> 3;
    const int sk = (tid & 7) * 4;
    const int* sg = &gx[sr * MAX_NB];
    const float* fa = fatoms + (size_t)(row0 + sr) * ATOM_FDIM;

    f32x4 acc[10];
#pragma unroll
    for (int t = 0; t < 10; ++t) acc[t] = (f32x4){0.f, 0.f, 0.f, 0.f};

    for (int k0 = 0; k0 < WTK_O; k0 += 32) {
        const int kk = k0 + sk;
        float s0, s1, s2, s3;
        if (kk + 4 <= ATOM_FDIM) {
            const float4 v = *(const float4*)&fa[kk];
            s0 = v.x; s1 = v.y; s2 = v.z; s3 = v.w;
        } else {
            const int kg = kk - ATOM_FDIM;   // >= 0 (136 % 4 == 0, no straddle)
            s0 = 0.f; s1 = 0.f; s2 = 0.f; s3 = 0.f;
#pragma unroll
            for (int j = 0; j < MAX_NB; ++j) {
                const __half2* p = (const __half2*)(msg + (size_t)sg[j] * HIDDEN + kg);
                const float2 u = __half22float2(p[0]);
                const float2 v = __half22float2(p[1]);
                s0 += u.x; s1 += u.y; s2 += v.x; s3 += v.y;
            }
        }
        uint2 ph, pl;
        split4(s0, s1, s2, s3, ph, pl);
        *(uint2*)&Ahi[sr * 40 + sk] = ph;
        *(uint2*)&Alo[sr * 40 + sk] = pl;
        __syncthreads();

        const bf16x8 ahi = *(const bf16x8*)&Ahi[mr * 40 + 8 * g];
        const bf16x8 alo = *(const bf16x8*)&Alo[mr * 40 + 8 * g];
        const int kb = k0 + 8 * g;

#pragma unroll
        for (int t = 0; t < 10; ++t) {
            if (t < ntile) {
                const int cn = 16 * (tbase + t) + (l & 15);
                const bf16x8 bhi = *(const bf16x8*)&wto_hi[(size_t)cn * WTK_O + kb];
                const bf16x8 blo = *(const bf16x8*)&wto_lo[(size_t)cn * WTK_O + kb];
                acc[t] = __builtin_amdgcn_mfma_f32_16x16x32_bf16(ahi, bhi, acc[t], 0, 0, 0);
                acc[t] = __builtin_amdgcn_mfma_f32_16x16x32_bf16(ahi, blo, acc[t], 0, 0, 0);
                acc[t] = __builtin_amdgcn_mfma_f32_16x16x32_bf16(alo, bhi, acc[t], 0, 0, 0);
            }
        }
        __syncthreads();
    }

#pragma unroll
    for (int t = 0; t < 10; ++t) {
        if (t < ntile) {
            const int col = 16 * (tbase + t) + (l & 15);
            if (col < HIDDEN) {
                const float bv = bias[col];
#pragma unroll
                for (int j = 0; j < 4; ++j) {
                    const size_t off = (size_t)(row0 + (w & 3) * 16 + 4 * g + j) * HIDDEN + col;
                    out0[off] = fmaxf(acc[t][j] + bv, 0.f);
                }
            }
        }
    }
}

// ---------------------------------------------------------------------------
// NEW: dense-A MFMA GEMM family (replaces fp32 gemm_fused modes 0/3/4).
//  MODE 0: A=fbonds fp32 [148] -> out0=fp16(A@W_i), out1=fp16(relu)
//  MODE 3: A=atom_h fp32 [300] -> out0=fp32(A@W_a)
//  MODE 4: A=P_all fp32 [300]  -> out[mol]=(hsum+sum_rows relu(A@W_b+bias))/32
// Same template as mp/mo; deterministic MODE-4 reduction via part[2][8][304]
// (each slot written by exactly one thread; fixed summation order; no atomics).
// ---------------------------------------------------------------------------
template<int MODE>
__global__ __launch_bounds__(512)
void gd_mfma(const float* __restrict__ A,
             const u16* __restrict__ wt_hi,
             const u16* __restrict__ wt_lo,
             const float* __restrict__ bias,
             const float* __restrict__ hsum,
             float* __restrict__ out0,
             float* __restrict__ out1)
{
    constexpr int K    = (MODE == 0) ? BOND_IN : HIDDEN;
    constexpr int KPAD = (MODE == 0) ? WTK_I : WTK_H;

    __shared__ u16 Ahi[64 * 40];
    __shared__ u16 Alo[64 * 40];

    const int tid  = threadIdx.x;
    const int row0 = blockIdx.x * 64;

    const int w  = tid >> 6;
    const int l  = tid & 63;
    const int g  = l >> 4;
    const int mr = (w & 3) * 16 + (l & 15);
    const int tbase = (w >> 2) ? 10 : 0;
    const int ntile = (w >> 2) ? 9 : 10;

    const int sr = tid >> 3;
    const int sk = (tid & 7) * 4;
    const float* ar = A + (size_t)(row0 + sr) * K;

    f32x4 acc[10];
#pragma unroll
    for (int t = 0; t < 10; ++t) acc[t] = (f32x4){0.f, 0.f, 0.f, 0.f};

    for (int k0 = 0; k0 < KPAD; k0 += 32) {
        const int kk = k0 + sk;
        float s0 = 0.f, s1 = 0.f, s2 = 0.f, s3 = 0.f;
        if (kk + 4 <= K) {               // K % 4 == 0 -> no straddle
            const float4 v = *(const float4*)&ar[kk];
            s0 = v.x; s1 = v.y; s2 = v.z; s3 = v.w;
        }
        uint2 ph, pl;
        split4(s0, s1, s2, s3, ph, pl);
        *(uint2*)&Ahi[sr * 40 + sk] = ph;
        *(uint2*)&Alo[sr * 40 + sk] = pl;
        __syncthreads();

        const bf16x8 ahi = *(const bf16x8*)&Ahi[mr * 40 + 8 * g];
        const bf16x8 alo = *(const bf16x8*)&Alo[mr * 40 + 8 * g];
        const int kb = k0 + 8 * g;

#pragma unroll
        for (int t = 0; t < 10; ++t) {
            if (t < ntile) {
                const int cn = 16 * (tbase + t) + (l & 15);
                const bf16x8 bhi = *(const bf16x8*)&wt_hi[(size_t)cn * KPAD + kb];
                const bf16x8 blo = *(const bf16x8*)&wt_lo[(size_t)cn * KPAD + kb];
                acc[t] = __builtin_amdgcn_mfma_f32_16x16x32_bf16(ahi, bhi, acc[t], 0, 0, 0);
                acc[t] = __builtin_amdgcn_mfma_f32_16x16x32_bf16(ahi, blo, acc[t], 0, 0, 0);
                acc[t] = __builtin_amdgcn_mfma_f32_16x16x32_bf16(alo, bhi, acc[t], 0, 0, 0);
            }
        }
        __syncthreads();
    }

    if constexpr (MODE == 4) {
        // deterministic per-molecule column reduction
        __shared__ float part[2][8][304];
        const int m    = (w & 3) >> 1;            // molecule half of this block
        const int cidx = ((w & 3) & 1) * 4 + g;   // contributor slot 0..7
#pragma unroll
        for (int t = 0; t < 10; ++t) {
            if (t < ntile) {
                const int col = 16 * (tbase + t) + (l & 15);
                const float bv = bias[col < HIDDEN ? col : 0];
                float s = 0.f;
#pragma unroll
                for (int j = 0; j < 4; ++j) s += fmaxf(acc[t][j] + bv, 0.f);
                part[m][cidx][col] = s;           // each (m,cidx,col) written once
            }
        }
        __syncthreads();
        const int m0 = blockIdx.x * 2;
        for (int t2 = tid; t2 < 2 * HIDDEN; t2 += 512) {
            const int mm = t2 / HIDDEN, col = t2 - mm * HIDDEN;
            float s = 0.f;
#pragma unroll
            for (int c = 0; c < 8; ++c) s += part[mm][c][col];
            const size_t o = (size_t)(m0 + mm) * HIDDEN + col;
            out0[o] = (s + hsum[o]) * (1.f / 32.f);
        }
        return;
    }

#pragma unroll
    for (int t = 0; t < 10; ++t) {
        if (t < ntile) {
            const int col = 16 * (tbase + t) + (l & 15);
            if (col < HIDDEN) {
#pragma unroll
                for (int j = 0; j < 4; ++j) {
                    const size_t off = (size_t)(row0 + (w & 3) * 16 + 4 * g + j) * HIDDEN + col;
                    const float v = acc[t][j];
                    if (MODE == 0) {
                        ((__half*)out0)[off] = __float2half(v);
                        ((__half*)out1)[off] = __float2half(fmaxf(v, 0.f));
                    } else {  // MODE 3
                        out0[off] = v;
                    }
                }
            }
        }
    }
}

// ---------------------------------------------------------------------------
// Per-molecule middle stage (proven): logits, softmax, P=att@h, hsum.
// ---------------------------------------------------------------------------
#define HSTR 320

__device__ __forceinline__ int hsw(int a, int c4u) {
    return a * HSTR + ((c4u ^ (a & 7)) << 2);
}

__global__ __launch_bounds__(512)
void attn_mid(const float* __restrict__ atom_h,
              const float* __restrict__ q_all,
              float* __restrict__ P_all,
              float* __restrict__ hsum)
{
    __shared__ float hs[APM * HSTR];
    __shared__ float qs[APM * HIDDEN];
    __shared__ float att[APM][33];

    const int tid  = threadIdx.x;
    const int wave = tid >> 6;
    const int lane = tid & 63;
    const int mol  = blockIdx.x;
    const float* hb = atom_h + (size_t)mol * APM * HIDDEN;
    const float* qb = q_all  + (size_t)mol * APM * HIDDEN;

    for (int j = tid; j < APM * 75; j += 512) {
        const int a = j / 75, c4u = j - a * 75;
        *(float4*)&hs[hsw(a, c4u)] = *(const float4*)&hb[(size_t)a * HIDDEN + 4 * c4u];
    }
    for (int j = tid; j < APM * 75; j += 512)
        *(float4*)&qs[4 * j] = *(const float4*)&qb[4 * j];
    __syncthreads();

    {
        const int a = tid >> 5, b = tid & 31;
        float s0 = 0.f, s1 = 0.f;
        for (int t = 0; t < 75; ++t) {
            const float4 hv = *(const float4*)&hs[hsw(b, t)];
            const float4 q0 = *(const float4*)&qs[a * HIDDEN + 4 * t];
            const float4 q1 = *(const float4*)&qs[(a + 16) * HIDDEN + 4 * t];
            s0 = fmaf(q0.x, hv.x, fmaf(q0.y, hv.y, fmaf(q0.z, hv.z, fmaf(q0.w, hv.w, s0))));
            s1 = fmaf(q1.x, hv.x, fmaf(q1.y, hv.y, fmaf(q1.z, hv.z, fmaf(q1.w, hv.w, s1))));
        }
        att[a][b] = s0;
        att[a + 16][b] = s1;
    }
    __syncthreads();

    if (tid < APM) {
        float m = -3.4e38f;
#pragma unroll 4
        for (int b = 0; b < APM; ++b) m = fmaxf(m, att[tid][b]);
        float s = 0.f;
#pragma unroll 4
        for (int b = 0; b < APM; ++b) { const float e = __expf(att[tid][b] - m); att[tid][b] = e; s += e; }
        const float inv = 1.f / s;
#pragma unroll 4
        for (int b = 0; b < APM; ++b) att[tid][b] *= inv;
    }
    __syncthreads();

    {
        const int r0 = wave * 4;
        const int c0 = 4 * lane;
        const bool has4 = (lane < 44);
        const int c4u = 64 + (lane >> 2), c4r = lane & 3;
        float4 p[4];
        float  p4[4];
#pragma unroll
        for (int r = 0; r < 4; ++r) { p[r] = make_float4(0,0,0,0); p4[r] = 0.f; }
#pragma unroll 4
        for (int b = 0; b < APM; ++b) {
            const float4 hv = *(const float4*)&hs[hsw(b, lane)];
            const float  h4 = hs[hsw(b, c4u) + c4r];
#pragma unroll
            for (int r = 0; r < 4; ++r) {
                const float av = att[r0 + r][b];
                p[r].x = fmaf(av, hv.x, p[r].x);
                p[r].y = fmaf(av, hv.y, p[r].y);
                p[r].z = fmaf(av, hv.z, p[r].z);
                p[r].w = fmaf(av, hv.w, p[r].w);
                p4[r]  = fmaf(av, h4,   p4[r]);
            }
        }
#pragma unroll
        for (int r = 0; r < 4; ++r) {
            const size_t off = ((size_t)mol * APM + r0 + r) * HIDDEN;
            *(float4*)&P_all[off + c0] = p[r];
            if (has4) P_all[off + 256 + lane] = p4[r];
        }
    }

    if (tid < HIDDEN) {
        const int c4u = tid >> 2, cr = tid & 3;
        float s = 0.f;
#pragma unroll 4
        for (int a = 0; a < APM; ++a) s += hs[hsw(a, c4u) + cr];
        hsum[(size_t)mol * HIDDEN + tid] = s;
    }
}

// ---------------------------------------------------------------------------
extern "C" void kernel_launch(void* const* d_in, const int* in_sizes, int n_in,
                              void* d_out, int out_size, void* d_ws, size_t ws_size,
                              hipStream_t stream)
{
    const float* fatoms = (const float*)d_in[0];
    const float* fbonds = (const float*)d_in[1];
    const int*   agraph = (const int*)d_in[2];
    const int*   bgraph = (const int*)d_in[3];
    const float* W_i    = (const float*)d_in[4];
    const float* W_h    = (const float*)d_in[5];
    const float* W_o    = (const float*)d_in[6];
    const float* b_o    = (const float*)d_in[7];
    const float* W_a    = (const float*)d_in[8];
    const float* W_b    = (const float*)d_in[9];
    const float* b_b    = (const float*)d_in[10];
    float* out = (float*)d_out;

    const size_t WB = (size_t)N_BONDS * HIDDEN;   // 78,643,200
    const size_t WA = (size_t)N_ATOMS * HIDDEN;   // 39,321,600
    // float-unit layout: binput_h(WB/2) | msgA(WB/2) | msgB(WB/2) |
    //   atom_h(WA) | q_all(WA) | P_all(WA) | hsum | wt region (476,672 floats)
    const size_t need = (3 * WB / 2 + 3 * WA + (size_t)N_MOLS * HIDDEN + 476672) * sizeof(float);
    float* base;
    if (ws_size >= need) {
        base = (float*)d_ws;
    } else {
        void* p = nullptr;
        (void)hipGetSymbolAddress(&p, HIP_SYMBOL(g_scratch));
        base = (float*)p;
    }
    __half* binput_h = (__half*)base;
    __half* msgA     = (__half*)(base + WB / 2);
    __half* msgB     = (__half*)(base + WB);
    float*  atom_h   = base + 3 * WB / 2;
    float*  q_all    = atom_h + WA;
    float*  P_all    = q_all + WA;
    float*  hsum     = P_all + WA;
    u16*    wth_hi   = (u16*)(hsum + (size_t)N_MOLS * HIDDEN);
    u16*    wth_lo   = wth_hi + WT_C * WTK_H;
    u16*    wto_hi   = wth_lo + WT_C * WTK_H;
    u16*    wto_lo   = wto_hi + WT_C * WTK_O;
    u16*    wti_hi   = wto_lo + WT_C * WTK_O;
    u16*    wti_lo   = wti_hi + WT_C * WTK_I;
    u16*    wta_hi   = wti_lo + WT_C * WTK_I;
    u16*    wta_lo   = wta_hi + WT_C * WTK_H;
    u16*    wtb_hi   = wta_lo + WT_C * WTK_H;
    u16*    wtb_lo   = wtb_hi + WT_C * WTK_H;

    const dim3 blk(512);

    // split/transpose all weights once per call
    wt_prep<<<(WT_C * WTK_H + 255) / 256, dim3(256), 0, stream>>>(W_h, wth_hi, wth_lo, HIDDEN, WTK_H);
    wt_prep<<<(WT_C * WTK_O + 255) / 256, dim3(256), 0, stream>>>(W_o, wto_hi, wto_lo, ATOM_FDIM + HIDDEN, WTK_O);
    wt_prep<<<(WT_C * WTK_I + 255) / 256, dim3(256), 0, stream>>>(W_i, wti_hi, wti_lo, BOND_IN, WTK_I);
    wt_prep<<<(WT_C * WTK_H + 255) / 256, dim3(256), 0, stream>>>(W_a, wta_hi, wta_lo, HIDDEN, WTK_H);
    wt_prep<<<(WT_C * WTK_H + 255) / 256, dim3(256), 0, stream>>>(W_b, wtb_hi, wtb_lo, HIDDEN, WTK_H);

    // binput_h = fp16(fbonds @ W_i) ; msgA = fp16(relu(...)) — MFMA
    gd_mfma<0><<<N_BONDS / 64, blk, 0, stream>>>(
        fbonds, wti_hi, wti_lo, nullptr, nullptr,
        (float*)binput_h, (float*)msgA);

    // 5 message-passing iterations — proven MFMA kernel
    const __half* cur = msgA;
    __half* nxt = msgB;
    for (int it = 0; it < 5; ++it) {
        mp_mfma<<<N_BONDS / 64, blk, 0, stream>>>(
            cur, bgraph, wth_hi, wth_lo, binput_h, nxt);
        __half* t = nxt; nxt = (__half*)cur; cur = t;
    }
    // final message in cur

    // atom_h = relu(concat(fatoms, gather6(msg)) @ W_o + b_o) — MFMA
    mo_mfma<<<N_ATOMS / 64, blk, 0, stream>>>(
        fatoms, cur, agraph, wto_hi, wto_lo, b_o, atom_h);

    // q_all = atom_h @ W_a — MFMA
    gd_mfma<3><<<N_ATOMS / 64, blk, 0, stream>>>(
        atom_h, wta_hi, wta_lo, nullptr, nullptr, q_all, nullptr);

    // per-molecule: logits, softmax, P = att@h, hsum
    attn_mid<<<N_MOLS, dim3(512), 0, stream>>>(atom_h, q_all, P_all, hsum);

    // out[mol] = (hsum + sum_rows relu(P @ W_b + b_b)) / 32 — MFMA
    gd_mfma<4><<<N_ATOMS / 64, blk, 0, stream>>>(
        P_all, wtb_hi, wtb_lo, b_b, hsum, out, nullptr);
}

// Round 16
// 6180.756 us; speedup vs baseline: 1.2744x; 1.0128x over previous
//
#include <hip/hip_runtime.h>
#include <hip/hip_fp16.h>
#include <math.h>

#define HIDDEN 300
#define ATOM_FDIM 136
#define BOND_IN 148
#define MAX_NB 6
#define N_MOLS 4096
#define APM 32
#define N_ATOMS (N_MOLS*APM)
#define N_BONDS (2*N_ATOMS)

// Wt (split-bf16, transposed) geometry: [304 cols][K padded] per split
#define WT_C 304
#define WTK_H 320   // W_h / W_a / W_b: K=300 padded
#define WTK_O 448   // W_o: K=436 padded
#define WTK_I 160   // W_i: K=148 padded

typedef unsigned short u16;
typedef short bf16x8 __attribute__((ext_vector_type(8)));
typedef float f32x4  __attribute__((ext_vector_type(4)));

// Fallback scratch if ws_size too small (float count of the layout below).
__device__ float g_scratch[3ull * N_BONDS * HIDDEN / 2 + 3ull * N_ATOMS * HIDDEN
                           + (size_t)N_MOLS * HIDDEN + 476672];

__device__ __forceinline__ u16 bf16_rne(float x) {
    unsigned u = __float_as_uint(x);
    unsigned r = (u + 0x7fffu + ((u >> 16) & 1u)) >> 16;
    return (u16)r;
}
__device__ __forceinline__ float bf16_f(u16 h) {
    return __uint_as_float(((unsigned)h) << 16);
}
__device__ __forceinline__ void st_h4(__half* p, float a, float b, float c, float d) {
    *(__half2*)(p)     = __floats2half2_rn(a, b);
    *(__half2*)(p + 2) = __floats2half2_rn(c, d);
}

// ---------------------------------------------------------------------------
// Prep: hi/lo[col][k] = split-bf16 of W[k][col], zero-padded to [WT_C][wtk]
// ---------------------------------------------------------------------------
__global__ __launch_bounds__(256)
void wt_prep(const float* __restrict__ W, u16* __restrict__ hi_out,
             u16* __restrict__ lo_out, int kact, int wtk)
{
    const int i = blockIdx.x * 256 + threadIdx.x;
    if (i >= WT_C * wtk) return;
    const int c = i / wtk, k = i - c * wtk;
    float w = (c < HIDDEN && k < kact) ? W[(size_t)k * HIDDEN + c] : 0.f;
    const u16 hi = bf16_rne(w);
    const u16 lo = bf16_rne(w - bf16_f(hi));
    hi_out[i] = hi;
    lo_out[i] = lo;
}

// ---------------------------------------------------------------------------
// Shared split helper: fp32 x4 -> packed bf16 hi/lo
// ---------------------------------------------------------------------------
__device__ __forceinline__ void split4(float s0, float s1, float s2, float s3,
                                       uint2& ph, uint2& pl)
{
    const u16 h0 = bf16_rne(s0), h1 = bf16_rne(s1), h2 = bf16_rne(s2), h3 = bf16_rne(s3);
    const u16 e0 = bf16_rne(s0 - bf16_f(h0)), e1 = bf16_rne(s1 - bf16_f(h1));
    const u16 e2 = bf16_rne(s2 - bf16_f(h2)), e3 = bf16_rne(s3 - bf16_f(h3));
    ph.x = (unsigned)h0 | ((unsigned)h1 << 16);
    ph.y = (unsigned)h2 | ((unsigned)h3 << 16);
    pl.x = (unsigned)e0 | ((unsigned)e1 << 16);
    pl.y = (unsigned)e2 | ((unsigned)e3 << 16);
}

// ---------------------------------------------------------------------------
// Message-passing step via MFMA (R14-proven, ~910 us = random-gather floor).
//   out0 = fp16( relu(binput + gather6(msg) @ W_h) )
// D map (m89): col = lane&15, row = (lane>>4)*4 + j.
// ---------------------------------------------------------------------------
__global__ __launch_bounds__(512)
void mp_mfma(const __half* __restrict__ msg,
             const int*   __restrict__ graph,
             const u16*   __restrict__ wt_hi,
             const u16*   __restrict__ wt_lo,
             const __half* __restrict__ binput,
             __half* __restrict__ out0)
{
    __shared__ u16 Ahi[64 * 40];
    __shared__ u16 Alo[64 * 40];
    __shared__ int gx[64 * MAX_NB];

    const int tid  = threadIdx.x;
    const int row0 = blockIdx.x * 64;

    if (tid < 64 * MAX_NB) gx[tid] = graph[(size_t)row0 * MAX_NB + tid];
    __syncthreads();

    const int w  = tid >> 6;
    const int l  = tid & 63;
    const int g  = l >> 4;
    const int mr = (w & 3) * 16 + (l & 15);
    const int tbase = (w >> 2) ? 10 : 0;
    const int ntile = (w >> 2) ? 9 : 10;

    const int sr = tid >> 3;
    const int sk = (tid & 7) * 4;
    const int* sg = &gx[sr * MAX_NB];

    f32x4 acc[10];
#pragma unroll
    for (int t = 0; t < 10; ++t) acc[t] = (f32x4){0.f, 0.f, 0.f, 0.f};

    for (int k0 = 0; k0 < HIDDEN; k0 += 32) {
        // stage A: fp16 gather -> fp32 sum -> split bf16 (tail reads past row
        // end hit finite data x zero-padded Wt -> products vanish; proven R7/R8)
        const int kk = k0 + sk;
        float s0 = 0.f, s1 = 0.f, s2 = 0.f, s3 = 0.f;
#pragma unroll
        for (int j = 0; j < MAX_NB; ++j) {
            const __half2* p = (const __half2*)(msg + (size_t)sg[j] * HIDDEN + kk);
            const float2 u = __half22float2(p[0]);
            const float2 v = __half22float2(p[1]);
            s0 += u.x; s1 += u.y; s2 += v.x; s3 += v.y;
        }
        uint2 ph, pl;
        split4(s0, s1, s2, s3, ph, pl);
        *(uint2*)&Ahi[sr * 40 + sk] = ph;
        *(uint2*)&Alo[sr * 40 + sk] = pl;
        __syncthreads();

        const bf16x8 ahi = *(const bf16x8*)&Ahi[mr * 40 + 8 * g];
        const bf16x8 alo = *(const bf16x8*)&Alo[mr * 40 + 8 * g];
        const int kb = k0 + 8 * g;

#pragma unroll
        for (int t = 0; t < 10; ++t) {
            if (t < ntile) {
                const int cn = 16 * (tbase + t) + (l & 15);
                const bf16x8 bhi = *(const bf16x8*)&wt_hi[(size_t)cn * WTK_H + kb];
                const bf16x8 blo = *(const bf16x8*)&wt_lo[(size_t)cn * WTK_H + kb];
                acc[t] = __builtin_amdgcn_mfma_f32_16x16x32_bf16(ahi, bhi, acc[t], 0, 0, 0);
                acc[t] = __builtin_amdgcn_mfma_f32_16x16x32_bf16(ahi, blo, acc[t], 0, 0, 0);
                acc[t] = __builtin_amdgcn_mfma_f32_16x16x32_bf16(alo, bhi, acc[t], 0, 0, 0);
            }
        }
        __syncthreads();
    }

#pragma unroll
    for (int t = 0; t < 10; ++t) {
        if (t < ntile) {
            const int col = 16 * (tbase + t) + (l & 15);
            if (col < HIDDEN) {
#pragma unroll
                for (int j = 0; j < 4; ++j) {
                    const size_t off = (size_t)(row0 + (w & 3) * 16 + 4 * g + j) * HIDDEN + col;
                    out0[off] = __float2half(fmaxf(__half2float(binput[off]) + acc[t][j], 0.f));
                }
            }
        }
    }
}

// ---------------------------------------------------------------------------
// Atom-hidden stage via MFMA (R14-proven):
//   atom_h = relu( concat(fatoms, gather6(msg, agraph)) @ W_o + b_o )  [fp32]
// ---------------------------------------------------------------------------
__global__ __launch_bounds__(512)
void mo_mfma(const float* __restrict__ fatoms,
             const __half* __restrict__ msg,
             const int*   __restrict__ graph,
             const u16*   __restrict__ wto_hi,
             const u16*   __restrict__ wto_lo,
             const float* __restrict__ bias,
             float* __restrict__ out0)
{
    __shared__ u16 Ahi[64 * 40];
    __shared__ u16 Alo[64 * 40];
    __shared__ int gx[64 * MAX_NB];

    const int tid  = threadIdx.x;
    const int row0 = blockIdx.x * 64;

    if (tid < 64 * MAX_NB) gx[tid] = graph[(size_t)row0 * MAX_NB + tid];
    __syncthreads();

    const int w  = tid >> 6;
    const int l  = tid & 63;
    const int g  = l >> 4;
    const int mr = (w & 3) * 16 + (l & 15);
    const int tbase = (w >> 2) ? 10 : 0;
    const int ntile = (w >> 2) ? 9 : 10;

    const int sr = tid >> 3;
    const int sk = (tid & 7) * 4;
    const int* sg = &gx[sr * MAX_NB];
    const float* fa = fatoms + (size_t)(row0 + sr) * ATOM_FDIM;

    f32x4 acc[10];
#pragma unroll
    for (int t = 0; t < 10; ++t) acc[t] = (f32x4){0.f, 0.f, 0.f, 0.f};

    for (int k0 = 0; k0 < WTK_O; k0 += 32) {
        const int kk = k0 + sk;
        float s0, s1, s2, s3;
        if (kk + 4 <= ATOM_FDIM) {
            const float4 v = *(const float4*)&fa[kk];
            s0 = v.x; s1 = v.y; s2 = v.z; s3 = v.w;
        } else {
            const int kg = kk - ATOM_FDIM;   // >= 0 (136 % 4 == 0, no straddle)
            s0 = 0.f; s1 = 0.f; s2 = 0.f; s3 = 0.f;
#pragma unroll
            for (int j = 0; j < MAX_NB; ++j) {
                const __half2* p = (const __half2*)(msg + (size_t)sg[j] * HIDDEN + kg);
                const float2 u = __half22float2(p[0]);
                const float2 v = __half22float2(p[1]);
                s0 += u.x; s1 += u.y; s2 += v.x; s3 += v.y;
            }
        }
        uint2 ph, pl;
        split4(s0, s1, s2, s3, ph, pl);
        *(uint2*)&Ahi[sr * 40 + sk] = ph;
        *(uint2*)&Alo[sr * 40 + sk] = pl;
        __syncthreads();

        const bf16x8 ahi = *(const bf16x8*)&Ahi[mr * 40 + 8 * g];
        const bf16x8 alo = *(const bf16x8*)&Alo[mr * 40 + 8 * g];
        const int kb = k0 + 8 * g;

#pragma unroll
        for (int t = 0; t < 10; ++t) {
            if (t < ntile) {
                const int cn = 16 * (tbase + t) + (l & 15);
                const bf16x8 bhi = *(const bf16x8*)&wto_hi[(size_t)cn * WTK_O + kb];
                const bf16x8 blo = *(const bf16x8*)&wto_lo[(size_t)cn * WTK_O + kb];
                acc[t] = __builtin_amdgcn_mfma_f32_16x16x32_bf16(ahi, bhi, acc[t], 0, 0, 0);
                acc[t] = __builtin_amdgcn_mfma_f32_16x16x32_bf16(ahi, blo, acc[t], 0, 0, 0);
                acc[t] = __builtin_amdgcn_mfma_f32_16x16x32_bf16(alo, bhi, acc[t], 0, 0, 0);
            }
        }
        __syncthreads();
    }

#pragma unroll
    for (int t = 0; t < 10; ++t) {
        if (t < ntile) {
            const int col = 16 * (tbase + t) + (l & 15);
            if (col < HIDDEN) {
                const float bv = bias[col];
#pragma unroll
                for (int j = 0; j < 4; ++j) {
                    const size_t off = (size_t)(row0 + (w & 3) * 16 + 4 * g + j) * HIDDEN + col;
                    out0[off] = fmaxf(acc[t][j] + bv, 0.f);
                }
            }
        }
    }
}

// ---------------------------------------------------------------------------
// Dense-A MFMA GEMM family (R15-proven).
//  MODE 0: A=fbonds fp32 [148] -> out0=fp16(A@W_i), out1=fp16(relu)
//  MODE 3: A=atom_h fp32 [300] -> out0=fp32(A@W_a)
//  MODE 4: A=P_all FP16 [300]  -> out[mol]=(hsum+sum_rows relu(A@W_b+bias))/32
// Deterministic MODE-4 reduction via part[2][8][304].
// ---------------------------------------------------------------------------
template<int MODE>
__global__ __launch_bounds__(512)
void gd_mfma(const void* __restrict__ Av,
             const u16* __restrict__ wt_hi,
             const u16* __restrict__ wt_lo,
             const float* __restrict__ bias,
             const float* __restrict__ hsum,
             float* __restrict__ out0,
             float* __restrict__ out1)
{
    constexpr int K    = (MODE == 0) ? BOND_IN : HIDDEN;
    constexpr int KPAD = (MODE == 0) ? WTK_I : WTK_H;

    __shared__ u16 Ahi[64 * 40];
    __shared__ u16 Alo[64 * 40];

    const int tid  = threadIdx.x;
    const int row0 = blockIdx.x * 64;

    const int w  = tid >> 6;
    const int l  = tid & 63;
    const int g  = l >> 4;
    const int mr = (w & 3) * 16 + (l & 15);
    const int tbase = (w >> 2) ? 10 : 0;
    const int ntile = (w >> 2) ? 9 : 10;

    const int sr = tid >> 3;
    const int sk = (tid & 7) * 4;

    f32x4 acc[10];
#pragma unroll
    for (int t = 0; t < 10; ++t) acc[t] = (f32x4){0.f, 0.f, 0.f, 0.f};

    for (int k0 = 0; k0 < KPAD; k0 += 32) {
        const int kk = k0 + sk;
        float s0 = 0.f, s1 = 0.f, s2 = 0.f, s3 = 0.f;
        if (kk + 4 <= K) {               // K % 4 == 0 -> no straddle
            if (MODE == 4) {
                const __half* ar = (const __half*)Av + (size_t)(row0 + sr) * K;
                const __half2* p = (const __half2*)(ar + kk);
                const float2 u = __half22float2(p[0]);
                const float2 v = __half22float2(p[1]);
                s0 = u.x; s1 = u.y; s2 = v.x; s3 = v.y;
            } else {
                const float* ar = (const float*)Av + (size_t)(row0 + sr) * K;
                const float4 v = *(const float4*)&ar[kk];
                s0 = v.x; s1 = v.y; s2 = v.z; s3 = v.w;
            }
        }
        uint2 ph, pl;
        split4(s0, s1, s2, s3, ph, pl);
        *(uint2*)&Ahi[sr * 40 + sk] = ph;
        *(uint2*)&Alo[sr * 40 + sk] = pl;
        __syncthreads();

        const bf16x8 ahi = *(const bf16x8*)&Ahi[mr * 40 + 8 * g];
        const bf16x8 alo = *(const bf16x8*)&Alo[mr * 40 + 8 * g];
        const int kb = k0 + 8 * g;

#pragma unroll
        for (int t = 0; t < 10; ++t) {
            if (t < ntile) {
                const int cn = 16 * (tbase + t) + (l & 15);
                const bf16x8 bhi = *(const bf16x8*)&wt_hi[(size_t)cn * KPAD + kb];
                const bf16x8 blo = *(const bf16x8*)&wt_lo[(size_t)cn * KPAD + kb];
                acc[t] = __builtin_amdgcn_mfma_f32_16x16x32_bf16(ahi, bhi, acc[t], 0, 0, 0);
                acc[t] = __builtin_amdgcn_mfma_f32_16x16x32_bf16(ahi, blo, acc[t], 0, 0, 0);
                acc[t] = __builtin_amdgcn_mfma_f32_16x16x32_bf16(alo, bhi, acc[t], 0, 0, 0);
            }
        }
        __syncthreads();
    }

    if constexpr (MODE == 4) {
        __shared__ float part[2][8][304];
        const int m    = (w & 3) >> 1;
        const int cidx = ((w & 3) & 1) * 4 + g;
#pragma unroll
        for (int t = 0; t < 10; ++t) {
            if (t < ntile) {
                const int col = 16 * (tbase + t) + (l & 15);
                const float bv = bias[col < HIDDEN ? col : 0];
                float s = 0.f;
#pragma unroll
                for (int j = 0; j < 4; ++j) s += fmaxf(acc[t][j] + bv, 0.f);
                part[m][cidx][col] = s;
            }
        }
        __syncthreads();
        const int m0 = blockIdx.x * 2;
        for (int t2 = tid; t2 < 2 * HIDDEN; t2 += 512) {
            const int mm = t2 / HIDDEN, col = t2 - mm * HIDDEN;
            float s = 0.f;
#pragma unroll
            for (int c = 0; c < 8; ++c) s += part[mm][c][col];
            const size_t o = (size_t)(m0 + mm) * HIDDEN + col;
            out0[o] = (s + hsum[o]) * (1.f / 32.f);
        }
        return;
    }

#pragma unroll
    for (int t = 0; t < 10; ++t) {
        if (t < ntile) {
            const int col = 16 * (tbase + t) + (l & 15);
            if (col < HIDDEN) {
#pragma unroll
                for (int j = 0; j < 4; ++j) {
                    const size_t off = (size_t)(row0 + (w & 3) * 16 + 4 * g + j) * HIDDEN + col;
                    const float v = acc[t][j];
                    if (MODE == 0) {
                        ((__half*)out0)[off] = __float2half(v);
                        ((__half*)out1)[off] = __float2half(fmaxf(v, 0.f));
                    } else {  // MODE 3
                        out0[off] = v;
                    }
                }
            }
        }
    }
}

// ---------------------------------------------------------------------------
// Per-molecule middle stage, v2: qs LDS tile DROPPED (q read from global via
// half-wave broadcast: `a` is uniform per 32 lanes -> one L1 line per access).
// LDS 82.6 -> 44.4 KB => 3 blocks/CU (was 1). P written fp16 (halves traffic;
// P ~ convex combo of h, fp16 error ~5e-4 rel, absorbed by absmax headroom).
// ---------------------------------------------------------------------------
#define HSTR 320

__device__ __forceinline__ int hsw(int a, int c4u) {
    return a * HSTR + ((c4u ^ (a & 7)) << 2);
}

__global__ __launch_bounds__(512)
void attn_mid(const float* __restrict__ atom_h,
              const float* __restrict__ q_all,
              __half* __restrict__ P_all,
              float* __restrict__ hsum)
{
    __shared__ float hs[APM * HSTR];   // 40 KB, swizzled
    __shared__ float att[APM][33];     // 4.2 KB

    const int tid  = threadIdx.x;
    const int wave = tid >> 6;
    const int lane = tid & 63;
    const int mol  = blockIdx.x;
    const float* hb = atom_h + (size_t)mol * APM * HIDDEN;
    const float* qb = q_all  + (size_t)mol * APM * HIDDEN;

    for (int j = tid; j < APM * 75; j += 512) {
        const int a = j / 75, c4u = j - a * 75;
        *(float4*)&hs[hsw(a, c4u)] = *(const float4*)&hb[(size_t)a * HIDDEN + 4 * c4u];
    }
    __syncthreads();

    // ---- logits: thread (a,b) and (a+16,b); q via global broadcast reads
    {
        const int a = tid >> 5, b = tid & 31;
        const float* q0p = qb + (size_t)a * HIDDEN;
        const float* q1p = qb + (size_t)(a + 16) * HIDDEN;
        float s0 = 0.f, s1 = 0.f;
        for (int t = 0; t < 75; ++t) {
            const float4 hv = *(const float4*)&hs[hsw(b, t)];
            const float4 q0 = *(const float4*)&q0p[4 * t];
            const float4 q1 = *(const float4*)&q1p[4 * t];
            s0 = fmaf(q0.x, hv.x, fmaf(q0.y, hv.y, fmaf(q0.z, hv.z, fmaf(q0.w, hv.w, s0))));
            s1 = fmaf(q1.x, hv.x, fmaf(q1.y, hv.y, fmaf(q1.z, hv.z, fmaf(q1.w, hv.w, s1))));
        }
        att[a][b] = s0;
        att[a + 16][b] = s1;
    }
    __syncthreads();

    // ---- softmax rows (max-subtracted; logits ~1e5-1e6)
    if (tid < APM) {
        float m = -3.4e38f;
#pragma unroll 4
        for (int b = 0; b < APM; ++b) m = fmaxf(m, att[tid][b]);
        float s = 0.f;
#pragma unroll 4
        for (int b = 0; b < APM; ++b) { const float e = __expf(att[tid][b] - m); att[tid][b] = e; s += e; }
        const float inv = 1.f / s;
#pragma unroll 4
        for (int b = 0; b < APM; ++b) att[tid][b] *= inv;
    }
    __syncthreads();

    // ---- P = att @ h -> fp16 store
    {
        const int r0 = wave * 4;
        const int c0 = 4 * lane;
        const bool has4 = (lane < 44);
        const int c4u = 64 + (lane >> 2), c4r = lane & 3;
        float4 p[4];
        float  p4[4];
#pragma unroll
        for (int r = 0; r < 4; ++r) { p[r] = make_float4(0,0,0,0); p4[r] = 0.f; }
#pragma unroll 4
        for (int b = 0; b < APM; ++b) {
            const float4 hv = *(const float4*)&hs[hsw(b, lane)];
            const float  h4 = hs[hsw(b, c4u) + c4r];
#pragma unroll
            for (int r = 0; r < 4; ++r) {
                const float av = att[r0 + r][b];
                p[r].x = fmaf(av, hv.x, p[r].x);
                p[r].y = fmaf(av, hv.y, p[r].y);
                p[r].z = fmaf(av, hv.z, p[r].z);
                p[r].w = fmaf(av, hv.w, p[r].w);
                p4[r]  = fmaf(av, h4,   p4[r]);
            }
        }
#pragma unroll
        for (int r = 0; r < 4; ++r) {
            const size_t off = ((size_t)mol * APM + r0 + r) * HIDDEN;
            st_h4(&P_all[off + c0], p[r].x, p[r].y, p[r].z, p[r].w);
            if (has4) P_all[off + 256 + lane] = __float2half(p4[r]);
        }
    }

    // ---- hsum[mol][c] = sum_a h[a][c]
    if (tid < HIDDEN) {
        const int c4u = tid >> 2, cr = tid & 3;
        float s = 0.f;
#pragma unroll 4
        for (int a = 0; a < APM; ++a) s += hs[hsw(a, c4u) + cr];
        hsum[(size_t)mol * HIDDEN + tid] = s;
    }
}

// ---------------------------------------------------------------------------
extern "C" void kernel_launch(void* const* d_in, const int* in_sizes, int n_in,
                              void* d_out, int out_size, void* d_ws, size_t ws_size,
                              hipStream_t stream)
{
    const float* fatoms = (const float*)d_in[0];
    const float* fbonds = (const float*)d_in[1];
    const int*   agraph = (const int*)d_in[2];
    const int*   bgraph = (const int*)d_in[3];
    const float* W_i    = (const float*)d_in[4];
    const float* W_h    = (const float*)d_in[5];
    const float* W_o    = (const float*)d_in[6];
    const float* b_o    = (const float*)d_in[7];
    const float* W_a    = (const float*)d_in[8];
    const float* W_b    = (const float*)d_in[9];
    const float* b_b    = (const float*)d_in[10];
    float* out = (float*)d_out;

    const size_t WB = (size_t)N_BONDS * HIDDEN;   // 78,643,200
    const size_t WA = (size_t)N_ATOMS * HIDDEN;   // 39,321,600
    // float-unit layout: binput_h(WB/2) | msgA(WB/2) | msgB(WB/2) |
    //   atom_h(WA) | q_all(WA) | P_all(WA/2 as fp16, slot kept WA) | hsum | wt
    const size_t need = (3 * WB / 2 + 3 * WA + (size_t)N_MOLS * HIDDEN + 476672) * sizeof(float);
    float* base;
    if (ws_size >= need) {
        base = (float*)d_ws;
    } else {
        void* p = nullptr;
        (void)hipGetSymbolAddress(&p, HIP_SYMBOL(g_scratch));
        base = (float*)p;
    }
    __half* binput_h = (__half*)base;
    __half* msgA     = (__half*)(base + WB / 2);
    __half* msgB     = (__half*)(base + WB);
    float*  atom_h   = base + 3 * WB / 2;
    float*  q_all    = atom_h + WA;
    __half* P_all    = (__half*)(q_all + WA);
    float*  hsum     = q_all + 2 * WA;
    u16*    wth_hi   = (u16*)(hsum + (size_t)N_MOLS * HIDDEN);
    u16*    wth_lo   = wth_hi + WT_C * WTK_H;
    u16*    wto_hi   = wth_lo + WT_C * WTK_H;
    u16*    wto_lo   = wto_hi + WT_C * WTK_O;
    u16*    wti_hi   = wto_lo + WT_C * WTK_O;
    u16*    wti_lo   = wti_hi + WT_C * WTK_I;
    u16*    wta_hi   = wti_lo + WT_C * WTK_I;
    u16*    wta_lo   = wta_hi + WT_C * WTK_H;
    u16*    wtb_hi   = wta_lo + WT_C * WTK_H;
    u16*    wtb_lo   = wtb_hi + WT_C * WTK_H;

    const dim3 blk(512);

    // split/transpose all weights once per call
    wt_prep<<<(WT_C * WTK_H + 255) / 256, dim3(256), 0, stream>>>(W_h, wth_hi, wth_lo, HIDDEN, WTK_H);
    wt_prep<<<(WT_C * WTK_O + 255) / 256, dim3(256), 0, stream>>>(W_o, wto_hi, wto_lo, ATOM_FDIM + HIDDEN, WTK_O);
    wt_prep<<<(WT_C * WTK_I + 255) / 256, dim3(256), 0, stream>>>(W_i, wti_hi, wti_lo, BOND_IN, WTK_I);
    wt_prep<<<(WT_C * WTK_H + 255) / 256, dim3(256), 0, stream>>>(W_a, wta_hi, wta_lo, HIDDEN, WTK_H);
    wt_prep<<<(WT_C * WTK_H + 255) / 256, dim3(256), 0, stream>>>(W_b, wtb_hi, wtb_lo, HIDDEN, WTK_H);

    // binput_h = fp16(fbonds @ W_i) ; msgA = fp16(relu(...)) — MFMA
    gd_mfma<0><<<N_BONDS / 64, blk, 0, stream>>>(
        fbonds, wti_hi, wti_lo, nullptr, nullptr,
        (float*)binput_h, (float*)msgA);

    // 5 message-passing iterations — proven MFMA kernel
    const __half* cur = msgA;
    __half* nxt = msgB;
    for (int it = 0; it < 5; ++it) {
        mp_mfma<<<N_BONDS / 64, blk, 0, stream>>>(
            cur, bgraph, wth_hi, wth_lo, binput_h, nxt);
        __half* t = nxt; nxt = (__half*)cur; cur = t;
    }
    // final message in cur

    // atom_h = relu(concat(fatoms, gather6(msg)) @ W_o + b_o) — MFMA
    mo_mfma<<<N_ATOMS / 64, blk, 0, stream>>>(
        fatoms, cur, agraph, wto_hi, wto_lo, b_o, atom_h);

    // q_all = atom_h @ W_a — MFMA
    gd_mfma<3><<<N_ATOMS / 64, blk, 0, stream>>>(
        atom_h, wta_hi, wta_lo, nullptr, nullptr, q_all, nullptr);

    // per-molecule: logits (q broadcast from global), softmax, P(fp16), hsum
    attn_mid<<<N_MOLS, dim3(512), 0, stream>>>(atom_h, q_all, P_all, hsum);

    // out[mol] = (hsum + sum_rows relu(P @ W_b + b_b)) / 32 — MFMA (fp16 A)
    gd_mfma<4><<<N_ATOMS / 64, blk, 0, stream>>>(
        P_all, wtb_hi, wtb_lo, b_b, hsum, out, nullptr);
}

// Round 17
// 6165.665 us; speedup vs baseline: 1.2775x; 1.0024x over previous
//
#include <hip/hip_runtime.h>
#include <hip/hip_fp16.h>
#include <math.h>

#define HIDDEN 300
#define ATOM_FDIM 136
#define BOND_IN 148
#define MAX_NB 6
#define N_MOLS 4096
#define APM 32
#define N_ATOMS (N_MOLS*APM)
#define N_BONDS (2*N_ATOMS)

// Wt (split-bf16, transposed) geometry: [304 cols][K padded] per split
#define WT_C 304
#define WTK_H 320   // W_h / W_a / W_b: K=300 padded
#define WTK_O 448   // W_o: K=436 padded
#define WTK_I 160   // W_i: K=148 padded

typedef unsigned short u16;
typedef short bf16x8 __attribute__((ext_vector_type(8)));
typedef float f32x4  __attribute__((ext_vector_type(4)));

// Fallback scratch if ws_size too small (float count of the layout below).
__device__ float g_scratch[3ull * N_BONDS * HIDDEN / 2 + 3ull * N_ATOMS * HIDDEN
                           + (size_t)N_MOLS * HIDDEN + 476672];

__device__ __forceinline__ u16 bf16_rne(float x) {
    unsigned u = __float_as_uint(x);
    unsigned r = (u + 0x7fffu + ((u >> 16) & 1u)) >> 16;
    return (u16)r;
}
__device__ __forceinline__ float bf16_f(u16 h) {
    return __uint_as_float(((unsigned)h) << 16);
}
__device__ __forceinline__ void st_h4(__half* p, float a, float b, float c, float d) {
    *(__half2*)(p)     = __floats2half2_rn(a, b);
    *(__half2*)(p + 2) = __floats2half2_rn(c, d);
}

// ---------------------------------------------------------------------------
// Prep: hi/lo[col][k] = split-bf16 of W[k][col], zero-padded to [WT_C][wtk]
// ---------------------------------------------------------------------------
__global__ __launch_bounds__(256)
void wt_prep(const float* __restrict__ W, u16* __restrict__ hi_out,
             u16* __restrict__ lo_out, int kact, int wtk)
{
    const int i = blockIdx.x * 256 + threadIdx.x;
    if (i >= WT_C * wtk) return;
    const int c = i / wtk, k = i - c * wtk;
    float w = (c < HIDDEN && k < kact) ? W[(size_t)k * HIDDEN + c] : 0.f;
    const u16 hi = bf16_rne(w);
    const u16 lo = bf16_rne(w - bf16_f(hi));
    hi_out[i] = hi;
    lo_out[i] = lo;
}

// ---------------------------------------------------------------------------
// Shared split helper: fp32 x4 -> packed bf16 hi/lo
// ---------------------------------------------------------------------------
__device__ __forceinline__ void split4(float s0, float s1, float s2, float s3,
                                       uint2& ph, uint2& pl)
{
    const u16 h0 = bf16_rne(s0), h1 = bf16_rne(s1), h2 = bf16_rne(s2), h3 = bf16_rne(s3);
    const u16 e0 = bf16_rne(s0 - bf16_f(h0)), e1 = bf16_rne(s1 - bf16_f(h1));
    const u16 e2 = bf16_rne(s2 - bf16_f(h2)), e3 = bf16_rne(s3 - bf16_f(h3));
    ph.x = (unsigned)h0 | ((unsigned)h1 << 16);
    ph.y = (unsigned)h2 | ((unsigned)h3 << 16);
    pl.x = (unsigned)e0 | ((unsigned)e1 << 16);
    pl.y = (unsigned)e2 | ((unsigned)e3 << 16);
}

// ---------------------------------------------------------------------------
// Message-passing step via MFMA (R14-proven, ~910 us = random-gather floor).
//   out0 = fp16( relu(binput + gather6(msg) @ W_h) )
// D map (m89): col = lane&15, row = (lane>>4)*4 + j.
// ---------------------------------------------------------------------------
__global__ __launch_bounds__(512)
void mp_mfma(const __half* __restrict__ msg,
             const int*   __restrict__ graph,
             const u16*   __restrict__ wt_hi,
             const u16*   __restrict__ wt_lo,
             const __half* __restrict__ binput,
             __half* __restrict__ out0)
{
    __shared__ u16 Ahi[64 * 40];
    __shared__ u16 Alo[64 * 40];
    __shared__ int gx[64 * MAX_NB];

    const int tid  = threadIdx.x;
    const int row0 = blockIdx.x * 64;

    if (tid < 64 * MAX_NB) gx[tid] = graph[(size_t)row0 * MAX_NB + tid];
    __syncthreads();

    const int w  = tid >> 6;
    const int l  = tid & 63;
    const int g  = l >> 4;
    const int mr = (w & 3) * 16 + (l & 15);
    const int tbase = (w >> 2) ? 10 : 0;
    const int ntile = (w >> 2) ? 9 : 10;

    const int sr = tid >> 3;
    const int sk = (tid & 7) * 4;
    const int* sg = &gx[sr * MAX_NB];

    f32x4 acc[10];
#pragma unroll
    for (int t = 0; t < 10; ++t) acc[t] = (f32x4){0.f, 0.f, 0.f, 0.f};

    for (int k0 = 0; k0 < HIDDEN; k0 += 32) {
        // stage A: fp16 gather -> fp32 sum -> split bf16 (tail reads past row
        // end hit finite data x zero-padded Wt -> products vanish; proven R7/R8)
        const int kk = k0 + sk;
        float s0 = 0.f, s1 = 0.f, s2 = 0.f, s3 = 0.f;
#pragma unroll
        for (int j = 0; j < MAX_NB; ++j) {
            const __half2* p = (const __half2*)(msg + (size_t)sg[j] * HIDDEN + kk);
            const float2 u = __half22float2(p[0]);
            const float2 v = __half22float2(p[1]);
            s0 += u.x; s1 += u.y; s2 += v.x; s3 += v.y;
        }
        uint2 ph, pl;
        split4(s0, s1, s2, s3, ph, pl);
        *(uint2*)&Ahi[sr * 40 + sk] = ph;
        *(uint2*)&Alo[sr * 40 + sk] = pl;
        __syncthreads();

        const bf16x8 ahi = *(const bf16x8*)&Ahi[mr * 40 + 8 * g];
        const bf16x8 alo = *(const bf16x8*)&Alo[mr * 40 + 8 * g];
        const int kb = k0 + 8 * g;

#pragma unroll
        for (int t = 0; t < 10; ++t) {
            if (t < ntile) {
                const int cn = 16 * (tbase + t) + (l & 15);
                const bf16x8 bhi = *(const bf16x8*)&wt_hi[(size_t)cn * WTK_H + kb];
                const bf16x8 blo = *(const bf16x8*)&wt_lo[(size_t)cn * WTK_H + kb];
                acc[t] = __builtin_amdgcn_mfma_f32_16x16x32_bf16(ahi, bhi, acc[t], 0, 0, 0);
                acc[t] = __builtin_amdgcn_mfma_f32_16x16x32_bf16(ahi, blo, acc[t], 0, 0, 0);
                acc[t] = __builtin_amdgcn_mfma_f32_16x16x32_bf16(alo, bhi, acc[t], 0, 0, 0);
            }
        }
        __syncthreads();
    }

#pragma unroll
    for (int t = 0; t < 10; ++t) {
        if (t < ntile) {
            const int col = 16 * (tbase + t) + (l & 15);
            if (col < HIDDEN) {
#pragma unroll
                for (int j = 0; j < 4; ++j) {
                    const size_t off = (size_t)(row0 + (w & 3) * 16 + 4 * g + j) * HIDDEN + col;
                    out0[off] = __float2half(fmaxf(__half2float(binput[off]) + acc[t][j], 0.f));
                }
            }
        }
    }
}

// ---------------------------------------------------------------------------
// Atom-hidden stage via MFMA (R14-proven):
//   atom_h = relu( concat(fatoms, gather6(msg, agraph)) @ W_o + b_o )  [fp32]
// ---------------------------------------------------------------------------
__global__ __launch_bounds__(512)
void mo_mfma(const float* __restrict__ fatoms,
             const __half* __restrict__ msg,
             const int*   __restrict__ graph,
             const u16*   __restrict__ wto_hi,
             const u16*   __restrict__ wto_lo,
             const float* __restrict__ bias,
             float* __restrict__ out0)
{
    __shared__ u16 Ahi[64 * 40];
    __shared__ u16 Alo[64 * 40];
    __shared__ int gx[64 * MAX_NB];

    const int tid  = threadIdx.x;
    const int row0 = blockIdx.x * 64;

    if (tid < 64 * MAX_NB) gx[tid] = graph[(size_t)row0 * MAX_NB + tid];
    __syncthreads();

    const int w  = tid >> 6;
    const int l  = tid & 63;
    const int g  = l >> 4;
    const int mr = (w & 3) * 16 + (l & 15);
    const int tbase = (w >> 2) ? 10 : 0;
    const int ntile = (w >> 2) ? 9 : 10;

    const int sr = tid >> 3;
    const int sk = (tid & 7) * 4;
    const int* sg = &gx[sr * MAX_NB];
    const float* fa = fatoms + (size_t)(row0 + sr) * ATOM_FDIM;

    f32x4 acc[10];
#pragma unroll
    for (int t = 0; t < 10; ++t) acc[t] = (f32x4){0.f, 0.f, 0.f, 0.f};

    for (int k0 = 0; k0 < WTK_O; k0 += 32) {
        const int kk = k0 + sk;
        float s0, s1, s2, s3;
        if (kk + 4 <= ATOM_FDIM) {
            const float4 v = *(const float4*)&fa[kk];
            s0 = v.x; s1 = v.y; s2 = v.z; s3 = v.w;
        } else {
            const int kg = kk - ATOM_FDIM;   // >= 0 (136 % 4 == 0, no straddle)
            s0 = 0.f; s1 = 0.f; s2 = 0.f; s3 = 0.f;
#pragma unroll
            for (int j = 0; j < MAX_NB; ++j) {
                const __half2* p = (const __half2*)(msg + (size_t)sg[j] * HIDDEN + kg);
                const float2 u = __half22float2(p[0]);
                const float2 v = __half22float2(p[1]);
                s0 += u.x; s1 += u.y; s2 += v.x; s3 += v.y;
            }
        }
        uint2 ph, pl;
        split4(s0, s1, s2, s3, ph, pl);
        *(uint2*)&Ahi[sr * 40 + sk] = ph;
        *(uint2*)&Alo[sr * 40 + sk] = pl;
        __syncthreads();

        const bf16x8 ahi = *(const bf16x8*)&Ahi[mr * 40 + 8 * g];
        const bf16x8 alo = *(const bf16x8*)&Alo[mr * 40 + 8 * g];
        const int kb = k0 + 8 * g;

#pragma unroll
        for (int t = 0; t < 10; ++t) {
            if (t < ntile) {
                const int cn = 16 * (tbase + t) + (l & 15);
                const bf16x8 bhi = *(const bf16x8*)&wto_hi[(size_t)cn * WTK_O + kb];
                const bf16x8 blo = *(const bf16x8*)&wto_lo[(size_t)cn * WTK_O + kb];
                acc[t] = __builtin_amdgcn_mfma_f32_16x16x32_bf16(ahi, bhi, acc[t], 0, 0, 0);
                acc[t] = __builtin_amdgcn_mfma_f32_16x16x32_bf16(ahi, blo, acc[t], 0, 0, 0);
                acc[t] = __builtin_amdgcn_mfma_f32_16x16x32_bf16(alo, bhi, acc[t], 0, 0, 0);
            }
        }
        __syncthreads();
    }

#pragma unroll
    for (int t = 0; t < 10; ++t) {
        if (t < ntile) {
            const int col = 16 * (tbase + t) + (l & 15);
            if (col < HIDDEN) {
                const float bv = bias[col];
#pragma unroll
                for (int j = 0; j < 4; ++j) {
                    const size_t off = (size_t)(row0 + (w & 3) * 16 + 4 * g + j) * HIDDEN + col;
                    out0[off] = fmaxf(acc[t][j] + bv, 0.f);
                }
            }
        }
    }
}

// ---------------------------------------------------------------------------
// Dense-A MFMA GEMM (R15-proven).
//  MODE 0: A=fbonds fp32 [148] -> out0=fp16(A@W_i), out1=fp16(relu)
//  MODE 3: A=atom_h fp32 [300] -> out0=fp32(A@W_a)
// ---------------------------------------------------------------------------
template<int MODE>
__global__ __launch_bounds__(512)
void gd_mfma(const void* __restrict__ Av,
             const u16* __restrict__ wt_hi,
             const u16* __restrict__ wt_lo,
             float* __restrict__ out0,
             float* __restrict__ out1)
{
    constexpr int K    = (MODE == 0) ? BOND_IN : HIDDEN;
    constexpr int KPAD = (MODE == 0) ? WTK_I : WTK_H;

    __shared__ u16 Ahi[64 * 40];
    __shared__ u16 Alo[64 * 40];

    const int tid  = threadIdx.x;
    const int row0 = blockIdx.x * 64;

    const int w  = tid >> 6;
    const int l  = tid & 63;
    const int g  = l >> 4;
    const int mr = (w & 3) * 16 + (l & 15);
    const int tbase = (w >> 2) ? 10 : 0;
    const int ntile = (w >> 2) ? 9 : 10;

    const int sr = tid >> 3;
    const int sk = (tid & 7) * 4;

    f32x4 acc[10];
#pragma unroll
    for (int t = 0; t < 10; ++t) acc[t] = (f32x4){0.f, 0.f, 0.f, 0.f};

    for (int k0 = 0; k0 < KPAD; k0 += 32) {
        const int kk = k0 + sk;
        float s0 = 0.f, s1 = 0.f, s2 = 0.f, s3 = 0.f;
        if (kk + 4 <= K) {               // K % 4 == 0 -> no straddle
            const float* ar = (const float*)Av + (size_t)(row0 + sr) * K;
            const float4 v = *(const float4*)&ar[kk];
            s0 = v.x; s1 = v.y; s2 = v.z; s3 = v.w;
        }
        uint2 ph, pl;
        split4(s0, s1, s2, s3, ph, pl);
        *(uint2*)&Ahi[sr * 40 + sk] = ph;
        *(uint2*)&Alo[sr * 40 + sk] = pl;
        __syncthreads();

        const bf16x8 ahi = *(const bf16x8*)&Ahi[mr * 40 + 8 * g];
        const bf16x8 alo = *(const bf16x8*)&Alo[mr * 40 + 8 * g];
        const int kb = k0 + 8 * g;

#pragma unroll
        for (int t = 0; t < 10; ++t) {
            if (t < ntile) {
                const int cn = 16 * (tbase + t) + (l & 15);
                const bf16x8 bhi = *(const bf16x8*)&wt_hi[(size_t)cn * KPAD + kb];
                const bf16x8 blo = *(const bf16x8*)&wt_lo[(size_t)cn * KPAD + kb];
                acc[t] = __builtin_amdgcn_mfma_f32_16x16x32_bf16(ahi, bhi, acc[t], 0, 0, 0);
                acc[t] = __builtin_amdgcn_mfma_f32_16x16x32_bf16(ahi, blo, acc[t], 0, 0, 0);
                acc[t] = __builtin_amdgcn_mfma_f32_16x16x32_bf16(alo, bhi, acc[t], 0, 0, 0);
            }
        }
        __syncthreads();
    }

#pragma unroll
    for (int t = 0; t < 10; ++t) {
        if (t < ntile) {
            const int col = 16 * (tbase + t) + (l & 15);
            if (col < HIDDEN) {
#pragma unroll
                for (int j = 0; j < 4; ++j) {
                    const size_t off = (size_t)(row0 + (w & 3) * 16 + 4 * g + j) * HIDDEN + col;
                    const float v = acc[t][j];
                    if (MODE == 0) {
                        ((__half*)out0)[off] = __float2half(v);
                        ((__half*)out1)[off] = __float2half(fmaxf(v, 0.f));
                    } else {  // MODE 3
                        out0[off] = v;
                    }
                }
            }
        }
    }
}

// ---------------------------------------------------------------------------
// Fused attention tail (NEW): logits -> softmax -> P -> [split-bf16 in LDS]
// -> MFMA P@W_b -> deterministic per-molecule reduce -> out[mol].
// LDS pool 52.9 KB, phase-aliased: [0,10496)f = hs | Phi+Plo;
// [10496,12928)f = att | part; [12928,13232)f = hsum_s. 3 blocks/CU.
// gd<4> + P_all/hsum round-trips eliminated. P error 2^-18 (was fp16 2^-11).
// ---------------------------------------------------------------------------
#define HSTR 320
#define PSTR 328   // P-tile row stride (u16): 656B -> 2-way banks (free)

__device__ __forceinline__ int hsw(int a, int c4u) {
    return a * HSTR + ((c4u ^ (a & 7)) << 2);
}

__global__ __launch_bounds__(512)
void attn_fused(const float* __restrict__ atom_h,
                const float* __restrict__ q_all,
                const u16* __restrict__ wtb_hi,
                const u16* __restrict__ wtb_lo,
                const float* __restrict__ bias,
                float* __restrict__ out)
{
    __shared__ __align__(16) float pool[13232];   // 52,928 B
    float* hs     = pool;                  // phase 1: [32][HSTR] swizzled
    u16*   Phi    = (u16*)pool;            // phase 2: [32][PSTR]
    u16*   Plo    = Phi + APM * PSTR;
    float* attb   = pool + 10496;          // phase 1: [32][33]
    float* part   = pool + 10496;          // phase 2: [8][304]
    float* hsum_s = pool + 12928;          // [304], live both phases

    const int tid  = threadIdx.x;
    const int wave = tid >> 6;
    const int lane = tid & 63;
    const int mol  = blockIdx.x;
    const float* hb = atom_h + (size_t)mol * APM * HIDDEN;
    const float* qb = q_all  + (size_t)mol * APM * HIDDEN;

    for (int j = tid; j < APM * 75; j += 512) {
        const int a = j / 75, c4u = j - a * 75;
        *(float4*)&hs[hsw(a, c4u)] = *(const float4*)&hb[(size_t)a * HIDDEN + 4 * c4u];
    }
    __syncthreads();

    // ---- logits: thread (a,b),(a+16,b); q via global half-wave broadcast
    {
        const int a = tid >> 5, b = tid & 31;
        const float* q0p = qb + (size_t)a * HIDDEN;
        const float* q1p = qb + (size_t)(a + 16) * HIDDEN;
        float s0 = 0.f, s1 = 0.f;
        for (int t = 0; t < 75; ++t) {
            const float4 hv = *(const float4*)&hs[hsw(b, t)];
            const float4 q0 = *(const float4*)&q0p[4 * t];
            const float4 q1 = *(const float4*)&q1p[4 * t];
            s0 = fmaf(q0.x, hv.x, fmaf(q0.y, hv.y, fmaf(q0.z, hv.z, fmaf(q0.w, hv.w, s0))));
            s1 = fmaf(q1.x, hv.x, fmaf(q1.y, hv.y, fmaf(q1.z, hv.z, fmaf(q1.w, hv.w, s1))));
        }
        attb[a * 33 + b] = s0;
        attb[(a + 16) * 33 + b] = s1;
    }
    __syncthreads();

    // ---- softmax rows (max-subtracted)
    if (tid < APM) {
        float m = -3.4e38f;
#pragma unroll 4
        for (int b = 0; b < APM; ++b) m = fmaxf(m, attb[tid * 33 + b]);
        float s = 0.f;
#pragma unroll 4
        for (int b = 0; b < APM; ++b) { const float e = __expf(attb[tid * 33 + b] - m); attb[tid * 33 + b] = e; s += e; }
        const float inv = 1.f / s;
#pragma unroll 4
        for (int b = 0; b < APM; ++b) attb[tid * 33 + b] *= inv;
    }
    __syncthreads();

    // ---- P = att @ h into registers; hsum into LDS (both read-only on hs)
    float4 p[4];
    float  p4v[4];
    {
        const int r0 = wave * 4;
        const int c4u = 64 + (lane >> 2), c4r = lane & 3;
#pragma unroll
        for (int r = 0; r < 4; ++r) { p[r] = make_float4(0,0,0,0); p4v[r] = 0.f; }
#pragma unroll 4
        for (int b = 0; b < APM; ++b) {
            const float4 hv = *(const float4*)&hs[hsw(b, lane)];
            const float  h4 = hs[hsw(b, c4u) + c4r];
#pragma unroll
            for (int r = 0; r < 4; ++r) {
                const float av = attb[(r0 + r) * 33 + b];
                p[r].x = fmaf(av, hv.x, p[r].x);
                p[r].y = fmaf(av, hv.y, p[r].y);
                p[r].z = fmaf(av, hv.z, p[r].z);
                p[r].w = fmaf(av, hv.w, p[r].w);
                p4v[r] = fmaf(av, h4,   p4v[r]);
            }
        }
    }
    if (tid < HIDDEN) {
        const int c4u = tid >> 2, cr = tid & 3;
        float s = 0.f;
#pragma unroll 4
        for (int a = 0; a < APM; ++a) s += hs[hsw(a, c4u) + cr];
        hsum_s[tid] = s;
    }
    __syncthreads();   // all hs/attb reads complete before overwrite

    // ---- split-bf16 P -> Phi/Plo (overwrites hs region); zero-pad k>=300
    {
        const int r0 = wave * 4;
        const int c0 = 4 * lane;
#pragma unroll
        for (int r = 0; r < 4; ++r) {
            uint2 ph, pl;
            split4(p[r].x, p[r].y, p[r].z, p[r].w, ph, pl);
            *(uint2*)&Phi[(r0 + r) * PSTR + c0] = ph;
            *(uint2*)&Plo[(r0 + r) * PSTR + c0] = pl;
            if (lane < 44) {
                const u16 h = bf16_rne(p4v[r]);
                const u16 e = bf16_rne(p4v[r] - bf16_f(h));
                Phi[(r0 + r) * PSTR + 256 + lane] = h;
                Plo[(r0 + r) * PSTR + 256 + lane] = e;
            }
        }
        for (int i = tid; i < APM * 28; i += 512) {
            const int r = i / 28, c = 300 + i - (i / 28) * 28;
            Phi[r * PSTR + c] = 0;
            Plo[r * PSTR + c] = 0;
        }
    }
    __syncthreads();

    // ---- MFMA: D(32x304) = P @ W_b ; wave -> (mt=w&1, ng=w>>1); no barriers
    {
        const int g   = lane >> 4;
        const int mt  = wave & 1;
        const int ng  = wave >> 1;
        const int tb2 = ng * 5;
        const int nt2 = (ng < 3) ? 5 : 4;
        const int mr  = mt * 16 + (lane & 15);

        f32x4 acc2[5];
#pragma unroll
        for (int t = 0; t < 5; ++t) acc2[t] = (f32x4){0.f, 0.f, 0.f, 0.f};

        for (int k0 = 0; k0 < WTK_H; k0 += 32) {
            const int kb = k0 + 8 * g;
            const bf16x8 ahi = *(const bf16x8*)&Phi[mr * PSTR + kb];
            const bf16x8 alo = *(const bf16x8*)&Plo[mr * PSTR + kb];
#pragma unroll
            for (int t = 0; t < 5; ++t) {
                if (t < nt2) {
                    const int cn = 16 * (tb2 + t) + (lane & 15);
                    const bf16x8 bhi = *(const bf16x8*)&wtb_hi[(size_t)cn * WTK_H + kb];
                    const bf16x8 blo = *(const bf16x8*)&wtb_lo[(size_t)cn * WTK_H + kb];
                    acc2[t] = __builtin_amdgcn_mfma_f32_16x16x32_bf16(ahi, bhi, acc2[t], 0, 0, 0);
                    acc2[t] = __builtin_amdgcn_mfma_f32_16x16x32_bf16(ahi, blo, acc2[t], 0, 0, 0);
                    acc2[t] = __builtin_amdgcn_mfma_f32_16x16x32_bf16(alo, bhi, acc2[t], 0, 0, 0);
                }
            }
        }

        // per-lane col partial: sum_j relu(acc2 + bias); slot = mt*4 + g
#pragma unroll
        for (int t = 0; t < 5; ++t) {
            if (t < nt2) {
                const int col = 16 * (tb2 + t) + (lane & 15);
                const float bv = bias[col < HIDDEN ? col : 0];
                float s = 0.f;
#pragma unroll
                for (int j = 0; j < 4; ++j) s += fmaxf(acc2[t][j] + bv, 0.f);
                part[(mt * 4 + g) * 304 + col] = s;   // single writer per slot
            }
        }
    }
    __syncthreads();

    // ---- out[mol] = (hsum + sum_slots part) / 32
    for (int c = tid; c < HIDDEN; c += 512) {
        float s = 0.f;
#pragma unroll
        for (int sl = 0; sl < 8; ++sl) s += part[sl * 304 + c];
        out[(size_t)mol * HIDDEN + c] = (s + hsum_s[c]) * (1.f / 32.f);
    }
}

// ---------------------------------------------------------------------------
extern "C" void kernel_launch(void* const* d_in, const int* in_sizes, int n_in,
                              void* d_out, int out_size, void* d_ws, size_t ws_size,
                              hipStream_t stream)
{
    const float* fatoms = (const float*)d_in[0];
    const float* fbonds = (const float*)d_in[1];
    const int*   agraph = (const int*)d_in[2];
    const int*   bgraph = (const int*)d_in[3];
    const float* W_i    = (const float*)d_in[4];
    const float* W_h    = (const float*)d_in[5];
    const float* W_o    = (const float*)d_in[6];
    const float* b_o    = (const float*)d_in[7];
    const float* W_a    = (const float*)d_in[8];
    const float* W_b    = (const float*)d_in[9];
    const float* b_b    = (const float*)d_in[10];
    float* out = (float*)d_out;

    const size_t WB = (size_t)N_BONDS * HIDDEN;   // 78,643,200
    const size_t WA = (size_t)N_ATOMS * HIDDEN;   // 39,321,600
    const size_t need = (3 * WB / 2 + 3 * WA + (size_t)N_MOLS * HIDDEN + 476672) * sizeof(float);
    float* base;
    if (ws_size >= need) {
        base = (float*)d_ws;
    } else {
        void* p = nullptr;
        (void)hipGetSymbolAddress(&p, HIP_SYMBOL(g_scratch));
        base = (float*)p;
    }
    __half* binput_h = (__half*)base;
    __half* msgA     = (__half*)(base + WB / 2);
    __half* msgB     = (__half*)(base + WB);
    float*  atom_h   = base + 3 * WB / 2;
    float*  q_all    = atom_h + WA;
    u16*    wth_hi   = (u16*)(q_all + 2 * WA + (size_t)N_MOLS * HIDDEN);  // keep prior offsets
    u16*    wth_lo   = wth_hi + WT_C * WTK_H;
    u16*    wto_hi   = wth_lo + WT_C * WTK_H;
    u16*    wto_lo   = wto_hi + WT_C * WTK_O;
    u16*    wti_hi   = wto_lo + WT_C * WTK_O;
    u16*    wti_lo   = wti_hi + WT_C * WTK_I;
    u16*    wta_hi   = wti_lo + WT_C * WTK_I;
    u16*    wta_lo   = wta_hi + WT_C * WTK_H;
    u16*    wtb_hi   = wta_lo + WT_C * WTK_H;
    u16*    wtb_lo   = wtb_hi + WT_C * WTK_H;

    const dim3 blk(512);

    // split/transpose all weights once per call
    wt_prep<<<(WT_C * WTK_H + 255) / 256, dim3(256), 0, stream>>>(W_h, wth_hi, wth_lo, HIDDEN, WTK_H);
    wt_prep<<<(WT_C * WTK_O + 255) / 256, dim3(256), 0, stream>>>(W_o, wto_hi, wto_lo, ATOM_FDIM + HIDDEN, WTK_O);
    wt_prep<<<(WT_C * WTK_I + 255) / 256, dim3(256), 0, stream>>>(W_i, wti_hi, wti_lo, BOND_IN, WTK_I);
    wt_prep<<<(WT_C * WTK_H + 255) / 256, dim3(256), 0, stream>>>(W_a, wta_hi, wta_lo, HIDDEN, WTK_H);
    wt_prep<<<(WT_C * WTK_H + 255) / 256, dim3(256), 0, stream>>>(W_b, wtb_hi, wtb_lo, HIDDEN, WTK_H);

    // binput_h = fp16(fbonds @ W_i) ; msgA = fp16(relu(...)) — MFMA
    gd_mfma<0><<<N_BONDS / 64, blk, 0, stream>>>(
        fbonds, wti_hi, wti_lo, (float*)binput_h, (float*)msgA);

    // 5 message-passing iterations — proven MFMA kernel
    const __half* cur = msgA;
    __half* nxt = msgB;
    for (int it = 0; it < 5; ++it) {
        mp_mfma<<<N_BONDS / 64, blk, 0, stream>>>(
            cur, bgraph, wth_hi, wth_lo, binput_h, nxt);
        __half* t = nxt; nxt = (__half*)cur; cur = t;
    }
    // final message in cur

    // atom_h = relu(concat(fatoms, gather6(msg)) @ W_o + b_o) — MFMA
    mo_mfma<<<N_ATOMS / 64, blk, 0, stream>>>(
        fatoms, cur, agraph, wto_hi, wto_lo, b_o, atom_h);

    // q_all = atom_h @ W_a — MFMA
    gd_mfma<3><<<N_ATOMS / 64, blk, 0, stream>>>(
        atom_h, wta_hi, wta_lo, q_all, nullptr);

    // fused attention tail: logits, softmax, P, P@W_b, reduce -> out
    attn_fused<<<N_MOLS, dim3(512), 0, stream>>>(
        atom_h, q_all, wtb_hi, wtb_lo, b_b, out);
}